// Round 7
// baseline (412.891 us; speedup 1.0000x reference)
//
#include <hip/hip_runtime.h>
#include <math.h>

#define D_MODEL 1024
#define D_HIDDEN 4096
#define NUM_HEADS 16
#define D_K 64
#define EPS 1e-6f
#define MASK_FILL -1e9f
#define BATCH 2
#define SEQ 2048
#define ROWS (BATCH * SEQ)   // 4096

typedef unsigned short ushort_t;
typedef __attribute__((ext_vector_type(8))) short bf16x8;
typedef __attribute__((ext_vector_type(4))) float f32x4;

__device__ __forceinline__ unsigned short f2bf(float f) {
    union { float f; unsigned int u; } v; v.f = f;
    unsigned int r = v.u + 0x7fffu + ((v.u >> 16) & 1u);   // RNE
    return (unsigned short)(r >> 16);
}
__device__ __forceinline__ float bf2f(unsigned short u) {
    union { unsigned int u; float f; } v; v.u = ((unsigned int)u) << 16;
    return v.f;
}

__device__ __forceinline__ void load_lds16(const void* g, void* l) {
    __builtin_amdgcn_global_load_lds(
        (__attribute__((address_space(1))) void*)g,
        (__attribute__((address_space(3))) void*)l,
        16, 0, 0);
}

// ---------------- LayerNorm: one block per row, writes bf16 ----------------
__global__ __launch_bounds__(256) void ln_kernel(const float* __restrict__ x,
                                                 const float* __restrict__ a,
                                                 const float* __restrict__ b,
                                                 ushort_t* __restrict__ out) {
    int row = blockIdx.x;
    int t = threadIdx.x;
    const float* xr = x + (size_t)row * D_MODEL;

    float4 v = ((const float4*)xr)[t];
    float s  = v.x + v.y + v.z + v.w;
    float ss = v.x*v.x + v.y*v.y + v.z*v.z + v.w*v.w;
    #pragma unroll
    for (int o = 32; o > 0; o >>= 1) {
        s  += __shfl_down(s,  o);
        ss += __shfl_down(ss, o);
    }
    __shared__ float ws0[4], ws1[4];
    __shared__ float mean_s, inv_s;
    int wid = t >> 6, lane = t & 63;
    if (lane == 0) { ws0[wid] = s; ws1[wid] = ss; }
    __syncthreads();
    if (t == 0) {
        float S1 = ws0[0] + ws0[1] + ws0[2] + ws0[3];
        float S2 = ws1[0] + ws1[1] + ws1[2] + ws1[3];
        float mean = S1 / (float)D_MODEL;
        float var  = (S2 - mean * S1) / (float)(D_MODEL - 1);  // Bessel
        mean_s = mean;
        inv_s  = 1.0f / (sqrtf(var) + EPS);
    }
    __syncthreads();
    float mean = mean_s, inv = inv_s;
    float4 av = ((const float4*)a)[t];
    float4 bv = ((const float4*)b)[t];
    ushort4 o;
    o.x = f2bf(av.x * (v.x - mean) * inv + bv.x);
    o.y = f2bf(av.y * (v.y - mean) * inv + bv.y);
    o.z = f2bf(av.z * (v.z - mean) * inv + bv.z);
    o.w = f2bf(av.w * (v.w - mean) * inv + bv.w);
    *(ushort4*)&out[(size_t)row * D_MODEL + (t << 2)] = o;
}

// ---------------- weight transpose + fp32->bf16: W[K][N] -> Wt[N][K] ----------------
__device__ __forceinline__ void transpose_tile(const float* W, ushort_t* Wt, int K, int N) {
    __shared__ float tile[64][65];
    int n0 = blockIdx.x * 64, k0 = blockIdx.y * 64;
    int t = threadIdx.x;
    int c4 = t & 15, r = t >> 4;
    #pragma unroll
    for (int p = 0; p < 4; p++) {
        int row = r + 16 * p;
        float4 v = *(const float4*)&W[(size_t)(k0 + row) * N + n0 + 4 * c4];
        tile[row][4*c4+0] = v.x; tile[row][4*c4+1] = v.y;
        tile[row][4*c4+2] = v.z; tile[row][4*c4+3] = v.w;
    }
    __syncthreads();
    #pragma unroll
    for (int p = 0; p < 4; p++) {
        int n = r + 16 * p;
        ushort4 o;
        o.x = f2bf(tile[4*c4+0][n]);
        o.y = f2bf(tile[4*c4+1][n]);
        o.z = f2bf(tile[4*c4+2][n]);
        o.w = f2bf(tile[4*c4+3][n]);
        *(ushort4*)&Wt[(size_t)(n0 + n) * K + k0 + 4 * c4] = o;
    }
}

__global__ __launch_bounds__(256) void transpose_bf16_kernel(const float* __restrict__ W,
                                                             ushort_t* __restrict__ Wt,
                                                             int K, int N) {
    transpose_tile(W, Wt, K, N);
}

// four 1024x1024 weights in one dispatch (grid z = 4)
__global__ __launch_bounds__(256) void transpose4_bf16_kernel(const float* s0, const float* s1,
                                                              const float* s2, const float* s3,
                                                              ushort_t* d0, ushort_t* d1,
                                                              ushort_t* d2, ushort_t* d3) {
    const float* S[4] = {s0, s1, s2, s3};
    ushort_t*    D[4] = {d0, d1, d2, d3};
    int z = blockIdx.z;
    transpose_tile(S[z], D[z], D_MODEL, D_MODEL);
}

// ---------------- bf16 MFMA GEMM, 128x128 tile ----------
// OUTMODE: 0 = f32 row-major (+resid), 1 = bf16 row-major, 3 = fused QKV epilogue
template<bool RELU, int OUTMODE>
__global__ __launch_bounds__(256) void gemm_mfma_128(const ushort_t* __restrict__ A,
                                                     const ushort_t* __restrict__ Bt,
                                                     const float* __restrict__ bias,
                                                     const float* __restrict__ resid,
                                                     void* __restrict__ Cout,
                                                     ushort_t* __restrict__ outk,
                                                     ushort_t* __restrict__ outvt,
                                                     int M, int N, int K) {
    __shared__ ushort_t As[128 * 32];   // [m][k], no padding (global_load_lds)
    __shared__ ushort_t Bs[128 * 32];   // [n][k]

    int tid = threadIdx.x;
    int wave = tid >> 6, lane = tid & 63;
    int m0 = blockIdx.y * 128, n0 = blockIdx.x * 128;

    int srow = 32 * wave + (lane >> 2);
    int sk   = (lane & 3) * 8;
    const ushort_t* gA = A  + (size_t)(m0 + srow) * K + sk;
    const ushort_t* gB = Bt + (size_t)(n0 + srow) * K + sk;
    ushort_t* lA = As + (32 * wave) * 32;
    ushort_t* lB = Bs + (32 * wave) * 32;

    f32x4 acc[4][4];
    #pragma unroll
    for (int i = 0; i < 4; i++)
        #pragma unroll
        for (int j = 0; j < 4; j++) acc[i][j] = (f32x4){0.f, 0.f, 0.f, 0.f};

    int wm = (wave >> 1) * 64, wn = (wave & 1) * 64;
    int fm = lane & 15;
    int fk = (lane >> 4) * 8;

    for (int k0 = 0; k0 < K; k0 += 32) {
        __syncthreads();
        load_lds16(gA,          lA);
        load_lds16(gA + 16 * K, lA + 16 * 32);
        load_lds16(gB,          lB);
        load_lds16(gB + 16 * K, lB + 16 * 32);
        gA += 32; gB += 32;
        __syncthreads();

        bf16x8 af[4], bfr[4];
        #pragma unroll
        for (int i = 0; i < 4; i++)
            af[i] = *(const bf16x8*)&As[(wm + 16 * i + fm) * 32 + fk];
        #pragma unroll
        for (int j = 0; j < 4; j++)
            bfr[j] = *(const bf16x8*)&Bs[(wn + 16 * j + fm) * 32 + fk];
        #pragma unroll
        for (int i = 0; i < 4; i++)
            #pragma unroll
            for (int j = 0; j < 4; j++)
                acc[i][j] = __builtin_amdgcn_mfma_f32_16x16x32_bf16(af[i], bfr[j], acc[i][j], 0, 0, 0);
    }

    // C/D map: col=lane&15, row=(lane>>4)*4+reg
    int col_l = lane & 15, row_l = (lane >> 4) * 4;
    #pragma unroll
    for (int i = 0; i < 4; i++) {
        #pragma unroll
        for (int j = 0; j < 4; j++) {
            int col = n0 + wn + 16 * j + col_l;
            if (OUTMODE == 3) {
                int row = m0 + wm + 16 * i + row_l;
                if (n0 < 1024) {
                    #pragma unroll
                    for (int r = 0; r < 4; r++)
                        ((ushort_t*)Cout)[(size_t)(row + r) * D_MODEL + col] = f2bf(acc[i][j][r]);
                } else if (n0 < 2048) {
                    #pragma unroll
                    for (int r = 0; r < 4; r++)
                        outk[(size_t)(row + r) * D_MODEL + (col - 1024)] = f2bf(acc[i][j][r]);
                } else {
                    int bb = row >> 11, s = row & 2047;
                    ushort4 o;
                    o.x = f2bf(acc[i][j][0]); o.y = f2bf(acc[i][j][1]);
                    o.z = f2bf(acc[i][j][2]); o.w = f2bf(acc[i][j][3]);
                    *(ushort4*)&outvt[((size_t)(bb * 1024 + (col - 2048))) * SEQ + s] = o;
                }
            } else {
                float bia = bias ? bias[col] : 0.f;
                #pragma unroll
                for (int r = 0; r < 4; r++) {
                    int row = m0 + wm + 16 * i + row_l + r;
                    float c = acc[i][j][r] + bia;
                    if (RELU) c = fmaxf(c, 0.f);
                    if (resid) c += resid[(size_t)row * N + col];
                    if (OUTMODE == 1)
                        ((ushort_t*)Cout)[(size_t)row * N + col] = f2bf(c);
                    else
                        ((float*)Cout)[(size_t)row * N + col] = c;
                }
            }
        }
    }
}

// ---------------- split-K bf16 GEMM ----------
__global__ __launch_bounds__(256) void gemm_splitk(const ushort_t* __restrict__ A,
                                                   const ushort_t* __restrict__ Bt,
                                                   ushort_t* __restrict__ P,
                                                   int M, int N, int K, int nsplit) {
    __shared__ ushort_t As[128 * 32];
    __shared__ ushort_t Bs[128 * 32];

    int tid = threadIdx.x;
    int wave = tid >> 6, lane = tid & 63;
    int m0 = blockIdx.y * 128, n0 = blockIdx.x * 128;
    int klen = K / nsplit, kbeg = blockIdx.z * klen;

    int srow = 32 * wave + (lane >> 2);
    int sk   = (lane & 3) * 8;
    const ushort_t* gA = A  + (size_t)(m0 + srow) * K + kbeg + sk;
    const ushort_t* gB = Bt + (size_t)(n0 + srow) * K + kbeg + sk;
    ushort_t* lA = As + (32 * wave) * 32;
    ushort_t* lB = Bs + (32 * wave) * 32;

    f32x4 acc[4][4];
    #pragma unroll
    for (int i = 0; i < 4; i++)
        #pragma unroll
        for (int j = 0; j < 4; j++) acc[i][j] = (f32x4){0.f, 0.f, 0.f, 0.f};

    int wm = (wave >> 1) * 64, wn = (wave & 1) * 64;
    int fm = lane & 15;
    int fk = (lane >> 4) * 8;

    for (int k0 = 0; k0 < klen; k0 += 32) {
        __syncthreads();
        load_lds16(gA,          lA);
        load_lds16(gA + 16 * K, lA + 16 * 32);
        load_lds16(gB,          lB);
        load_lds16(gB + 16 * K, lB + 16 * 32);
        gA += 32; gB += 32;
        __syncthreads();

        bf16x8 af[4], bfr[4];
        #pragma unroll
        for (int i = 0; i < 4; i++)
            af[i] = *(const bf16x8*)&As[(wm + 16 * i + fm) * 32 + fk];
        #pragma unroll
        for (int j = 0; j < 4; j++)
            bfr[j] = *(const bf16x8*)&Bs[(wn + 16 * j + fm) * 32 + fk];
        #pragma unroll
        for (int i = 0; i < 4; i++)
            #pragma unroll
            for (int j = 0; j < 4; j++)
                acc[i][j] = __builtin_amdgcn_mfma_f32_16x16x32_bf16(af[i], bfr[j], acc[i][j], 0, 0, 0);
    }

    ushort_t* Pz = P + (size_t)blockIdx.z * M * N;
    int col_l = lane & 15, row_l = (lane >> 4) * 4;
    #pragma unroll
    for (int i = 0; i < 4; i++)
        #pragma unroll
        for (int j = 0; j < 4; j++) {
            int col = n0 + wn + 16 * j + col_l;
            #pragma unroll
            for (int r = 0; r < 4; r++) {
                int row = m0 + wm + 16 * i + row_l + r;
                Pz[(size_t)row * N + col] = f2bf(acc[i][j][r]);
            }
        }
}

// out = sum_z P[z] + x2 + b2 ; one block per row
__global__ __launch_bounds__(256) void ffn2_reduce(const ushort_t* __restrict__ P,
                                                   const float* __restrict__ x2,
                                                   const float* __restrict__ b2,
                                                   float* __restrict__ out) {
    int row = blockIdx.x, t = threadIdx.x;
    const size_t MN = (size_t)ROWS * D_MODEL;
    size_t off = (size_t)row * D_MODEL + (t << 2);
    float4 acc = *(const float4*)&x2[off];
    float4 bb  = *(const float4*)&b2[t << 2];
    acc.x += bb.x; acc.y += bb.y; acc.z += bb.z; acc.w += bb.w;
    #pragma unroll
    for (int s = 0; s < 4; s++) {
        ushort4 u = *(const ushort4*)&P[s * MN + off];
        acc.x += bf2f(u.x); acc.y += bf2f(u.y);
        acc.z += bf2f(u.z); acc.w += bf2f(u.w);
    }
    *(float4*)&out[off] = acc;
}

// ---------------- bf16 MFMA GEMM, 128x64 tile ----------
template<bool RELU>
__global__ __launch_bounds__(256) void gemm_mfma_64(const ushort_t* __restrict__ A,
                                                    const ushort_t* __restrict__ Bt,
                                                    const float* __restrict__ bias,
                                                    const float* __restrict__ resid,
                                                    float* __restrict__ Cout,
                                                    int M, int N, int K) {
    __shared__ ushort_t As[128 * 32];
    __shared__ ushort_t Bs[64 * 32];

    int tid = threadIdx.x;
    int wave = tid >> 6, lane = tid & 63;
    int m0 = blockIdx.y * 128, n0 = blockIdx.x * 64;

    int arow = 32 * wave + (lane >> 2);
    int brow = 16 * wave + (lane >> 2);
    int sk   = (lane & 3) * 8;
    const ushort_t* gA = A  + (size_t)(m0 + arow) * K + sk;
    const ushort_t* gB = Bt + (size_t)(n0 + brow) * K + sk;
    ushort_t* lA = As + (32 * wave) * 32;
    ushort_t* lB = Bs + (16 * wave) * 32;

    f32x4 acc[2][4];
    #pragma unroll
    for (int i = 0; i < 2; i++)
        #pragma unroll
        for (int j = 0; j < 4; j++) acc[i][j] = (f32x4){0.f, 0.f, 0.f, 0.f};

    int wm = 32 * wave;
    int fm = lane & 15;
    int fk = (lane >> 4) * 8;

    for (int k0 = 0; k0 < K; k0 += 32) {
        __syncthreads();
        load_lds16(gA,          lA);
        load_lds16(gA + 16 * K, lA + 16 * 32);
        load_lds16(gB,          lB);
        gA += 32; gB += 32;
        __syncthreads();

        bf16x8 af[2], bfr[4];
        #pragma unroll
        for (int i = 0; i < 2; i++)
            af[i] = *(const bf16x8*)&As[(wm + 16 * i + fm) * 32 + fk];
        #pragma unroll
        for (int j = 0; j < 4; j++)
            bfr[j] = *(const bf16x8*)&Bs[(16 * j + fm) * 32 + fk];
        #pragma unroll
        for (int i = 0; i < 2; i++)
            #pragma unroll
            for (int j = 0; j < 4; j++)
                acc[i][j] = __builtin_amdgcn_mfma_f32_16x16x32_bf16(af[i], bfr[j], acc[i][j], 0, 0, 0);
    }

    int col_l = lane & 15, row_l = (lane >> 4) * 4;
    #pragma unroll
    for (int i = 0; i < 2; i++) {
        #pragma unroll
        for (int j = 0; j < 4; j++) {
            int col = n0 + 16 * j + col_l;
            float bia = bias ? bias[col] : 0.f;
            #pragma unroll
            for (int r = 0; r < 4; r++) {
                int row = m0 + wm + 16 * i + row_l + r;
                float c = acc[i][j][r] + bia;
                if (RELU) c = fmaxf(c, 0.f);
                if (resid) c += resid[(size_t)row * N + col];
                Cout[(size_t)row * N + col] = c;
            }
        }
    }
}

// ---------------- MFMA flash attention, S^T form, 64-row Q tiles ----------------
// Block = (64-row Q tile, head, batch); grid 32x16x2 = 1024 blocks (4/CU).
// QK^T computed operand-swapped (A=K, B=Q) so each lane's 4 acc regs are 4
// CONSECUTIVE KEYS of one q-row -> packed b64 P-stores, cheap mask/exp fold.
__global__ __launch_bounds__(256) void fattn_mfma(const ushort_t* __restrict__ Q,
                                                  const ushort_t* __restrict__ K,
                                                  const ushort_t* __restrict__ Vt,
                                                  const int* __restrict__ mask,
                                                  ushort_t* __restrict__ O) {
    __shared__ ushort_t Ks[64 * 64];    // [k][d], chunk-swizzled
    __shared__ ushort_t Vs[64 * 64];    // [d][k], chunk-swizzled
    __shared__ ushort_t Pt[64 * 68];    // [q][k], padded (+4)

    int tid = threadIdx.x, wave = tid >> 6, lane = tid & 63;
    int qt = blockIdx.x, h = blockIdx.y, b = blockIdx.z;
    int q0 = qt * 64;
    int l8 = lane >> 3, c8 = lane & 7;
    int cg = c8 ^ l8;                   // swizzled source chunk (row&7 == l8)

    const ushort_t* Kg = K + ((size_t)(b * SEQ)) * D_MODEL + h * 64;
    const ushort_t* Vg = Vt + ((size_t)(b * 1024 + h * 64)) * SEQ;

    int fm = lane & 15, fq = lane >> 4;
    int fk = fq * 8;
    int swz = (fm & 7) * 8;
    const float C2 = 0.18033688f;       // 0.125 * log2(e)

    // Q as B-operand fragments: wave covers q-rows [q0+16w, q0+16w+16), n=fm
    bf16x8 qf[2];
    {
        int row = q0 + wave * 16 + fm;
        const ushort_t* qr = Q + (size_t)(b * SEQ + row) * D_MODEL + h * 64;
        qf[0] = *(const bf16x8*)&qr[fk];
        qf[1] = *(const bf16x8*)&qr[32 + fk];
    }

    float l_acc = 0.f;                  // partial softmax denom for q = fm
    f32x4 acc_o[4];                     // 4 d-tiles; C: col=d(16j+fm), row=q(fq*4+r)
    #pragma unroll
    for (int j = 0; j < 4; j++) acc_o[j] = (f32x4){0.f, 0.f, 0.f, 0.f};

    for (int kt = 0; kt < SEQ / 64; kt++) {
        int k0 = kt * 64;
        __syncthreads();    // prev iter done reading Ks/Vs/Pt
        #pragma unroll
        for (int c = 0; c < 2; c++) {
            int row = c * 32 + wave * 8 + l8;
            load_lds16(Kg + (size_t)(k0 + row) * D_MODEL + cg * 8, &Ks[(c * 32 + wave * 8) * 64]);
            load_lds16(Vg + (size_t)row * SEQ + k0 + cg * 8,        &Vs[(c * 32 + wave * 8) * 64]);
        }
        __syncthreads();    // staging drained

        // ---- S^T = K Q^T : tiles over 4 key-groups ----
        f32x4 sT[4];
        #pragma unroll
        for (int jk = 0; jk < 4; jk++) sT[jk] = (f32x4){0.f, 0.f, 0.f, 0.f};
        #pragma unroll
        for (int kh = 0; kh < 2; kh++) {
            bf16x8 kf[4];
            #pragma unroll
            for (int jk = 0; jk < 4; jk++)
                kf[jk] = *(const bf16x8*)&Ks[(16 * jk + fm) * 64 + ((kh * 32 + fk) ^ swz)];
            #pragma unroll
            for (int jk = 0; jk < 4; jk++)
                sT[jk] = __builtin_amdgcn_mfma_f32_16x16x32_bf16(kf[jk], qf[kh], sT[jk], 0, 0, 0);
        }

        // ---- mask fold + exp2 + l accumulate; lane's keys: 16jk + 4fq + r ----
        const int* mrow = mask + b * SEQ + k0;
        #pragma unroll
        for (int jk = 0; jk < 4; jk++) {
            int4 mv = *(const int4*)&mrow[16 * jk + 4 * fq];
            float bias0 = mv.x ? 0.f : -1000.f;
            float bias1 = mv.y ? 0.f : -1000.f;
            float bias2 = mv.z ? 0.f : -1000.f;
            float bias3 = mv.w ? 0.f : -1000.f;
            sT[jk][0] = exp2f(fmaf(sT[jk][0], C2, bias0));
            sT[jk][1] = exp2f(fmaf(sT[jk][1], C2, bias1));
            sT[jk][2] = exp2f(fmaf(sT[jk][2], C2, bias2));
            sT[jk][3] = exp2f(fmaf(sT[jk][3], C2, bias3));
            l_acc += sT[jk][0] + sT[jk][1] + sT[jk][2] + sT[jk][3];
        }

        // ---- packed P store: 4 consecutive keys -> one b64 per jk ----
        {
            ushort_t* prow = &Pt[(wave * 16 + fm) * 68];
            #pragma unroll
            for (int jk = 0; jk < 4; jk++) {
                unsigned u0 = __float_as_uint(sT[jk][0]) + 0x8000u;
                unsigned u1 = __float_as_uint(sT[jk][1]) + 0x8000u;
                unsigned u2 = __float_as_uint(sT[jk][2]) + 0x8000u;
                unsigned u3 = __float_as_uint(sT[jk][3]) + 0x8000u;
                uint2 pk;
                pk.x = __builtin_amdgcn_perm(u1, u0, 0x07060302u);
                pk.y = __builtin_amdgcn_perm(u3, u2, 0x07060302u);
                *(uint2*)&prow[16 * jk + 4 * fq] = pk;
            }
        }
        __syncthreads();    // Pt visible

        // ---- O += P V : A = P (m=q), B = V^T (n=d) ----
        #pragma unroll
        for (int kh = 0; kh < 2; kh++) {
            bf16x8 pf, vf[4];
            pf = *(const bf16x8*)&Pt[(wave * 16 + fm) * 68 + kh * 32 + fk];
            #pragma unroll
            for (int j = 0; j < 4; j++)
                vf[j] = *(const bf16x8*)&Vs[(16 * j + fm) * 64 + ((kh * 32 + fk) ^ swz)];
            #pragma unroll
            for (int j = 0; j < 4; j++)
                acc_o[j] = __builtin_amdgcn_mfma_f32_16x16x32_bf16(pf, vf[j], acc_o[j], 0, 0, 0);
        }
    }

    // ---- epilogue: reduce l across quads (q = fm), redistribute, store ----
    float l_full = l_acc;
    l_full += __shfl_xor(l_full, 16);
    l_full += __shfl_xor(l_full, 32);
    #pragma unroll
    for (int r = 0; r < 4; r++) {
        float lr = __shfl(l_full, fq * 4 + r);   // l for q-row fq*4+r
        float inv = 1.0f / lr;
        int row = q0 + wave * 16 + fq * 4 + r;
        #pragma unroll
        for (int j = 0; j < 4; j++) {
            int col = h * 64 + 16 * j + fm;
            O[(size_t)(b * SEQ + row) * D_MODEL + col] = f2bf(acc_o[j][r] * inv);
        }
    }
}

// ---------------- launch ----------------
extern "C" void kernel_launch(void* const* d_in, const int* in_sizes, int n_in,
                              void* d_out, int out_size, void* d_ws, size_t ws_size,
                              hipStream_t stream) {
    const float* x    = (const float*)d_in[0];
    const int*   mask = (const int*)  d_in[1];
    const float* wq   = (const float*)d_in[2];
    const float* wk   = (const float*)d_in[3];
    const float* wv   = (const float*)d_in[4];
    const float* wo   = (const float*)d_in[5];
    const float* w1   = (const float*)d_in[6];
    const float* b1   = (const float*)d_in[7];
    const float* w2   = (const float*)d_in[8];
    const float* b2   = (const float*)d_in[9];
    const float* ln1a = (const float*)d_in[10];
    const float* ln1b = (const float*)d_in[11];
    const float* ln2a = (const float*)d_in[12];
    const float* ln2b = (const float*)d_in[13];
    float* out = (float*)d_out;

    char* ws = (char*)d_ws;
    const size_t MB = 1024 * 1024;
    float*    x2    = (float*)   (ws + 0 * MB);    // 16 MB
    ushort_t* hbf   = (ushort_t*)(ws + 16 * MB);   // 8 MB (LN1/attn/LN2 out)
    ushort_t* qbf   = (ushort_t*)(ws + 24 * MB);   // 8 MB
    ushort_t* kbf   = (ushort_t*)(ws + 32 * MB);   // 8 MB
    ushort_t* vtbf  = (ushort_t*)(ws + 40 * MB);   // 8 MB (V transposed)
    ushort_t* ffbf  = (ushort_t*)(ws + 48 * MB);   // 32 MB
    ushort_t* wqkvt = (ushort_t*)(ws + 80 * MB);   // 6 MB: wq|wk|wv transposed
    ushort_t* wot   = (ushort_t*)(ws + 86 * MB);   // 2 MB
    ushort_t* w1t   = (ushort_t*)(ws + 88 * MB);   // 8 MB
    ushort_t* w2t   = (ushort_t*)(ws + 96 * MB);   // 8 MB
    // FFN2 split-K partials (32 MB) reuse hbf/qbf/kbf/vtbf — all dead after FFN1
    ushort_t* pbuf  = (ushort_t*)(ws + 16 * MB);

    ushort_t* wqt = wqkvt;
    ushort_t* wkt = wqkvt + (size_t)1024 * 1024;
    ushort_t* wvt = wqkvt + (size_t)2 * 1024 * 1024;

    dim3 blk(256);

    transpose4_bf16_kernel<<<dim3(16, 16, 4), blk, 0, stream>>>(wq, wk, wv, wo, wqt, wkt, wvt, wot);
    transpose_bf16_kernel<<<dim3(64, 16), blk, 0, stream>>>(w1, w1t, D_MODEL, D_HIDDEN);
    transpose_bf16_kernel<<<dim3(16, 64), blk, 0, stream>>>(w2, w2t, D_HIDDEN, D_MODEL);

    ln_kernel<<<ROWS, blk, 0, stream>>>(x, ln1a, ln1b, hbf);

    // fused QKV: N = 3072, epilogue routes to qbf / kbf / vtbf
    dim3 g_qkv(3 * D_MODEL / 128, ROWS / 128);
    gemm_mfma_128<false, 3><<<g_qkv, blk, 0, stream>>>(hbf, wqkvt, nullptr, nullptr,
                                                       qbf, kbf, vtbf, ROWS, 3 * D_MODEL, D_MODEL);

    dim3 g_attn(SEQ / 64, NUM_HEADS, BATCH);
    fattn_mfma<<<g_attn, blk, 0, stream>>>(qbf, kbf, vtbf, mask, hbf);

    // x2 = x + attn @ wo
    dim3 g_wo(D_MODEL / 64, ROWS / 128);
    gemm_mfma_64<false><<<g_wo, blk, 0, stream>>>(hbf, wot, nullptr, x, x2, ROWS, D_MODEL, D_MODEL);

    ln_kernel<<<ROWS, blk, 0, stream>>>(x2, ln2a, ln2b, hbf);

    // ff = relu(h2 @ w1 + b1)
    dim3 g_ff1(D_HIDDEN / 128, ROWS / 128);
    gemm_mfma_128<true, 1><<<g_ff1, blk, 0, stream>>>(hbf, w1t, b1, nullptr, ffbf,
                                                      nullptr, nullptr, ROWS, D_HIDDEN, D_MODEL);

    // FFN2 split-K=4 into bf16 partials, then fused reduce with resid + bias
    dim3 g_ff2(D_MODEL / 128, ROWS / 128, 4);
    gemm_splitk<<<g_ff2, blk, 0, stream>>>(ffbf, w2t, pbuf, ROWS, D_MODEL, D_HIDDEN, 4);
    ffn2_reduce<<<ROWS, blk, 0, stream>>>(pbuf, x2, b2, out);
}

// Round 8
// 387.771 us; speedup vs baseline: 1.0648x; 1.0648x over previous
//
#include <hip/hip_runtime.h>
#include <math.h>

#define D_MODEL 1024
#define D_HIDDEN 4096
#define NUM_HEADS 16
#define D_K 64
#define EPS 1e-6f
#define MASK_FILL -1e9f
#define BATCH 2
#define SEQ 2048
#define ROWS (BATCH * SEQ)   // 4096

typedef unsigned short ushort_t;
typedef __attribute__((ext_vector_type(8))) short bf16x8;
typedef __attribute__((ext_vector_type(4))) float f32x4;

__device__ __forceinline__ unsigned short f2bf(float f) {
    union { float f; unsigned int u; } v; v.f = f;
    unsigned int r = v.u + 0x7fffu + ((v.u >> 16) & 1u);   // RNE
    return (unsigned short)(r >> 16);
}
__device__ __forceinline__ float bf2f(unsigned short u) {
    union { unsigned int u; float f; } v; v.u = ((unsigned int)u) << 16;
    return v.f;
}

__device__ __forceinline__ void load_lds16(const void* g, void* l) {
    __builtin_amdgcn_global_load_lds(
        (__attribute__((address_space(1))) void*)g,
        (__attribute__((address_space(3))) void*)l,
        16, 0, 0);
}

// ---------------- LayerNorm ----------------
__global__ __launch_bounds__(256) void ln_kernel(const float* __restrict__ x,
                                                 const float* __restrict__ a,
                                                 const float* __restrict__ b,
                                                 ushort_t* __restrict__ out) {
    int row = blockIdx.x;
    int t = threadIdx.x;
    const float* xr = x + (size_t)row * D_MODEL;

    float4 v = ((const float4*)xr)[t];
    float s  = v.x + v.y + v.z + v.w;
    float ss = v.x*v.x + v.y*v.y + v.z*v.z + v.w*v.w;
    #pragma unroll
    for (int o = 32; o > 0; o >>= 1) {
        s  += __shfl_down(s,  o);
        ss += __shfl_down(ss, o);
    }
    __shared__ float ws0[4], ws1[4];
    __shared__ float mean_s, inv_s;
    int wid = t >> 6, lane = t & 63;
    if (lane == 0) { ws0[wid] = s; ws1[wid] = ss; }
    __syncthreads();
    if (t == 0) {
        float S1 = ws0[0] + ws0[1] + ws0[2] + ws0[3];
        float S2 = ws1[0] + ws1[1] + ws1[2] + ws1[3];
        float mean = S1 / (float)D_MODEL;
        float var  = (S2 - mean * S1) / (float)(D_MODEL - 1);  // Bessel
        mean_s = mean;
        inv_s  = 1.0f / (sqrtf(var) + EPS);
    }
    __syncthreads();
    float mean = mean_s, inv = inv_s;
    float4 av = ((const float4*)a)[t];
    float4 bv = ((const float4*)b)[t];
    ushort4 o;
    o.x = f2bf(av.x * (v.x - mean) * inv + bv.x);
    o.y = f2bf(av.y * (v.y - mean) * inv + bv.y);
    o.z = f2bf(av.z * (v.z - mean) * inv + bv.z);
    o.w = f2bf(av.w * (v.w - mean) * inv + bv.w);
    *(ushort4*)&out[(size_t)row * D_MODEL + (t << 2)] = o;
}

// ---------------- weight transpose fp32->bf16: W[K][N] -> Wt[N][K] ----------------
__device__ __forceinline__ void transpose_tile(const float* W, ushort_t* Wt, int K, int N) {
    __shared__ float tile[64][65];
    int n0 = blockIdx.x * 64, k0 = blockIdx.y * 64;
    int t = threadIdx.x;
    int c4 = t & 15, r = t >> 4;
    #pragma unroll
    for (int p = 0; p < 4; p++) {
        int row = r + 16 * p;
        float4 v = *(const float4*)&W[(size_t)(k0 + row) * N + n0 + 4 * c4];
        tile[row][4*c4+0] = v.x; tile[row][4*c4+1] = v.y;
        tile[row][4*c4+2] = v.z; tile[row][4*c4+3] = v.w;
    }
    __syncthreads();
    #pragma unroll
    for (int p = 0; p < 4; p++) {
        int n = r + 16 * p;
        ushort4 o;
        o.x = f2bf(tile[4*c4+0][n]);
        o.y = f2bf(tile[4*c4+1][n]);
        o.z = f2bf(tile[4*c4+2][n]);
        o.w = f2bf(tile[4*c4+3][n]);
        *(ushort4*)&Wt[(size_t)(n0 + n) * K + k0 + 4 * c4] = o;
    }
}

__global__ __launch_bounds__(256) void transpose_bf16_kernel(const float* __restrict__ W,
                                                             ushort_t* __restrict__ Wt,
                                                             int K, int N) {
    transpose_tile(W, Wt, K, N);
}

__global__ __launch_bounds__(256) void transpose4_bf16_kernel(const float* s0, const float* s1,
                                                              const float* s2, const float* s3,
                                                              ushort_t* d0, ushort_t* d1,
                                                              ushort_t* d2, ushort_t* d3) {
    const float* S[4] = {s0, s1, s2, s3};
    ushort_t*    D[4] = {d0, d1, d2, d3};
    int z = blockIdx.z;
    transpose_tile(S[z], D[z], D_MODEL, D_MODEL);
}

// ---------------- mask prefix scan: list of unmasked key indices + count ----------------
__global__ __launch_bounds__(256) void mask_scan_kernel(const int* __restrict__ mask,
                                                        int* __restrict__ idx,
                                                        int* __restrict__ nun) {
    int b = blockIdx.x, t = threadIdx.x;
    __shared__ int sums[256];
    const int* m = mask + b * SEQ;
    int loc[8], s = 0;
    #pragma unroll
    for (int i = 0; i < 8; i++) { loc[i] = m[t * 8 + i]; s += loc[i]; }
    sums[t] = s;
    __syncthreads();
    for (int off = 1; off < 256; off <<= 1) {
        int v = sums[t];
        if (t >= off) v += sums[t - off];
        __syncthreads();
        sums[t] = v;
        __syncthreads();
    }
    int c = (t > 0) ? sums[t - 1] : 0;   // exclusive prefix
    #pragma unroll
    for (int i = 0; i < 8; i++)
        if (loc[i]) { idx[b * SEQ + c] = t * 8 + i; c++; }
    if (t == 255) nun[b] = sums[255];
}

// ---------------- gather compacted K/V rows (zero-pad tail) ----------------
__global__ __launch_bounds__(256) void gather_kv_kernel(const ushort_t* __restrict__ Ksrc,
                                                        const ushort_t* __restrict__ Vsrc,
                                                        const int* __restrict__ idx,
                                                        const int* __restrict__ nun,
                                                        ushort_t* __restrict__ K2,
                                                        ushort_t* __restrict__ V2) {
    int j = blockIdx.x, b = blockIdx.y, t = threadIdx.x;
    int n = nun[b];
    size_t drow = ((size_t)b * SEQ + j) * D_MODEL;
    if (j < n) {
        size_t srow = ((size_t)b * SEQ + idx[b * SEQ + j]) * D_MODEL;
        ((ushort4*)&K2[drow])[t] = ((const ushort4*)&Ksrc[srow])[t];
        ((ushort4*)&V2[drow])[t] = ((const ushort4*)&Vsrc[srow])[t];
    } else {
        ushort4 z = {0, 0, 0, 0};
        ((ushort4*)&K2[drow])[t] = z;
        ((ushort4*)&V2[drow])[t] = z;
    }
}

// ---------------- bf16 64x64 transpose: V2[b][s][d] -> Vt2[b][d][s] ----------------
__global__ __launch_bounds__(256) void transpose_v_kernel(const ushort_t* __restrict__ V2,
                                                          ushort_t* __restrict__ Vt2) {
    __shared__ ushort_t tile[64][68];
    int n0 = blockIdx.x * 64, s0 = blockIdx.y * 64, b = blockIdx.z;
    int t = threadIdx.x;
    int c4 = t & 15, r = t >> 4;
    const ushort_t* src = V2 + (size_t)b * SEQ * D_MODEL;
    ushort_t* dst = Vt2 + (size_t)b * D_MODEL * SEQ;
    #pragma unroll
    for (int p = 0; p < 4; p++) {
        int row = r + 16 * p;
        ushort4 v = *(const ushort4*)&src[(size_t)(s0 + row) * D_MODEL + n0 + 4 * c4];
        tile[row][4*c4+0] = v.x; tile[row][4*c4+1] = v.y;
        tile[row][4*c4+2] = v.z; tile[row][4*c4+3] = v.w;
    }
    __syncthreads();
    #pragma unroll
    for (int p = 0; p < 4; p++) {
        int n = r + 16 * p;
        ushort4 o;
        o.x = tile[4*c4+0][n]; o.y = tile[4*c4+1][n];
        o.z = tile[4*c4+2][n]; o.w = tile[4*c4+3][n];
        *(ushort4*)&dst[(size_t)(n0 + n) * SEQ + s0 + 4 * c4] = o;
    }
}

// ---------------- bf16 MFMA GEMM, 128x128 tile ----------
// OUTMODE: 0 = f32 row-major (+resid), 1 = bf16 row-major, 3 = fused QKV (all row-major)
template<bool RELU, int OUTMODE>
__global__ __launch_bounds__(256) void gemm_mfma_128(const ushort_t* __restrict__ A,
                                                     const ushort_t* __restrict__ Bt,
                                                     const float* __restrict__ bias,
                                                     const float* __restrict__ resid,
                                                     void* __restrict__ Cout,
                                                     ushort_t* __restrict__ outk,
                                                     ushort_t* __restrict__ outv,
                                                     int M, int N, int K) {
    __shared__ ushort_t As[128 * 32];
    __shared__ ushort_t Bs[128 * 32];

    int tid = threadIdx.x;
    int wave = tid >> 6, lane = tid & 63;
    int m0 = blockIdx.y * 128, n0 = blockIdx.x * 128;

    int srow = 32 * wave + (lane >> 2);
    int sk   = (lane & 3) * 8;
    const ushort_t* gA = A  + (size_t)(m0 + srow) * K + sk;
    const ushort_t* gB = Bt + (size_t)(n0 + srow) * K + sk;
    ushort_t* lA = As + (32 * wave) * 32;
    ushort_t* lB = Bs + (32 * wave) * 32;

    f32x4 acc[4][4];
    #pragma unroll
    for (int i = 0; i < 4; i++)
        #pragma unroll
        for (int j = 0; j < 4; j++) acc[i][j] = (f32x4){0.f, 0.f, 0.f, 0.f};

    int wm = (wave >> 1) * 64, wn = (wave & 1) * 64;
    int fm = lane & 15;
    int fk = (lane >> 4) * 8;

    for (int k0 = 0; k0 < K; k0 += 32) {
        __syncthreads();
        load_lds16(gA,          lA);
        load_lds16(gA + 16 * K, lA + 16 * 32);
        load_lds16(gB,          lB);
        load_lds16(gB + 16 * K, lB + 16 * 32);
        gA += 32; gB += 32;
        __syncthreads();

        bf16x8 af[4], bfr[4];
        #pragma unroll
        for (int i = 0; i < 4; i++)
            af[i] = *(const bf16x8*)&As[(wm + 16 * i + fm) * 32 + fk];
        #pragma unroll
        for (int j = 0; j < 4; j++)
            bfr[j] = *(const bf16x8*)&Bs[(wn + 16 * j + fm) * 32 + fk];
        #pragma unroll
        for (int i = 0; i < 4; i++)
            #pragma unroll
            for (int j = 0; j < 4; j++)
                acc[i][j] = __builtin_amdgcn_mfma_f32_16x16x32_bf16(af[i], bfr[j], acc[i][j], 0, 0, 0);
    }

    int col_l = lane & 15, row_l = (lane >> 4) * 4;
    #pragma unroll
    for (int i = 0; i < 4; i++) {
        #pragma unroll
        for (int j = 0; j < 4; j++) {
            int col = n0 + wn + 16 * j + col_l;
            if (OUTMODE == 3) {
                int row = m0 + wm + 16 * i + row_l;
                ushort_t* dst;
                int c;
                if (n0 < 1024)      { dst = (ushort_t*)Cout; c = col; }
                else if (n0 < 2048) { dst = outk; c = col - 1024; }
                else                { dst = outv; c = col - 2048; }
                #pragma unroll
                for (int r = 0; r < 4; r++)
                    dst[(size_t)(row + r) * D_MODEL + c] = f2bf(acc[i][j][r]);
            } else {
                float bia = bias ? bias[col] : 0.f;
                #pragma unroll
                for (int r = 0; r < 4; r++) {
                    int row = m0 + wm + 16 * i + row_l + r;
                    float c = acc[i][j][r] + bia;
                    if (RELU) c = fmaxf(c, 0.f);
                    if (resid) c += resid[(size_t)row * N + col];
                    if (OUTMODE == 1)
                        ((ushort_t*)Cout)[(size_t)row * N + col] = f2bf(c);
                    else
                        ((float*)Cout)[(size_t)row * N + col] = c;
                }
            }
        }
    }
}

// ---------------- split-K bf16 GEMM ----------
__global__ __launch_bounds__(256) void gemm_splitk(const ushort_t* __restrict__ A,
                                                   const ushort_t* __restrict__ Bt,
                                                   ushort_t* __restrict__ P,
                                                   int M, int N, int K, int nsplit) {
    __shared__ ushort_t As[128 * 32];
    __shared__ ushort_t Bs[128 * 32];

    int tid = threadIdx.x;
    int wave = tid >> 6, lane = tid & 63;
    int m0 = blockIdx.y * 128, n0 = blockIdx.x * 128;
    int klen = K / nsplit, kbeg = blockIdx.z * klen;

    int srow = 32 * wave + (lane >> 2);
    int sk   = (lane & 3) * 8;
    const ushort_t* gA = A  + (size_t)(m0 + srow) * K + kbeg + sk;
    const ushort_t* gB = Bt + (size_t)(n0 + srow) * K + kbeg + sk;
    ushort_t* lA = As + (32 * wave) * 32;
    ushort_t* lB = Bs + (32 * wave) * 32;

    f32x4 acc[4][4];
    #pragma unroll
    for (int i = 0; i < 4; i++)
        #pragma unroll
        for (int j = 0; j < 4; j++) acc[i][j] = (f32x4){0.f, 0.f, 0.f, 0.f};

    int wm = (wave >> 1) * 64, wn = (wave & 1) * 64;
    int fm = lane & 15;
    int fk = (lane >> 4) * 8;

    for (int k0 = 0; k0 < klen; k0 += 32) {
        __syncthreads();
        load_lds16(gA,          lA);
        load_lds16(gA + 16 * K, lA + 16 * 32);
        load_lds16(gB,          lB);
        load_lds16(gB + 16 * K, lB + 16 * 32);
        gA += 32; gB += 32;
        __syncthreads();

        bf16x8 af[4], bfr[4];
        #pragma unroll
        for (int i = 0; i < 4; i++)
            af[i] = *(const bf16x8*)&As[(wm + 16 * i + fm) * 32 + fk];
        #pragma unroll
        for (int j = 0; j < 4; j++)
            bfr[j] = *(const bf16x8*)&Bs[(wn + 16 * j + fm) * 32 + fk];
        #pragma unroll
        for (int i = 0; i < 4; i++)
            #pragma unroll
            for (int j = 0; j < 4; j++)
                acc[i][j] = __builtin_amdgcn_mfma_f32_16x16x32_bf16(af[i], bfr[j], acc[i][j], 0, 0, 0);
    }

    ushort_t* Pz = P + (size_t)blockIdx.z * M * N;
    int col_l = lane & 15, row_l = (lane >> 4) * 4;
    #pragma unroll
    for (int i = 0; i < 4; i++)
        #pragma unroll
        for (int j = 0; j < 4; j++) {
            int col = n0 + wn + 16 * j + col_l;
            #pragma unroll
            for (int r = 0; r < 4; r++) {
                int row = m0 + wm + 16 * i + row_l + r;
                Pz[(size_t)row * N + col] = f2bf(acc[i][j][r]);
            }
        }
}

// out = sum_z P[z] + x2 + b2
__global__ __launch_bounds__(256) void ffn2_reduce(const ushort_t* __restrict__ P,
                                                   const float* __restrict__ x2,
                                                   const float* __restrict__ b2,
                                                   float* __restrict__ out) {
    int row = blockIdx.x, t = threadIdx.x;
    const size_t MN = (size_t)ROWS * D_MODEL;
    size_t off = (size_t)row * D_MODEL + (t << 2);
    float4 acc = *(const float4*)&x2[off];
    float4 bb  = *(const float4*)&b2[t << 2];
    acc.x += bb.x; acc.y += bb.y; acc.z += bb.z; acc.w += bb.w;
    #pragma unroll
    for (int s = 0; s < 4; s++) {
        ushort4 u = *(const ushort4*)&P[s * MN + off];
        acc.x += bf2f(u.x); acc.y += bf2f(u.y);
        acc.z += bf2f(u.z); acc.w += bf2f(u.w);
    }
    *(float4*)&out[off] = acc;
}

// ---------------- bf16 MFMA GEMM, 128x64 tile ----------
template<bool RELU>
__global__ __launch_bounds__(256) void gemm_mfma_64(const ushort_t* __restrict__ A,
                                                    const ushort_t* __restrict__ Bt,
                                                    const float* __restrict__ bias,
                                                    const float* __restrict__ resid,
                                                    float* __restrict__ Cout,
                                                    int M, int N, int K) {
    __shared__ ushort_t As[128 * 32];
    __shared__ ushort_t Bs[64 * 32];

    int tid = threadIdx.x;
    int wave = tid >> 6, lane = tid & 63;
    int m0 = blockIdx.y * 128, n0 = blockIdx.x * 64;

    int arow = 32 * wave + (lane >> 2);
    int brow = 16 * wave + (lane >> 2);
    int sk   = (lane & 3) * 8;
    const ushort_t* gA = A  + (size_t)(m0 + arow) * K + sk;
    const ushort_t* gB = Bt + (size_t)(n0 + brow) * K + sk;
    ushort_t* lA = As + (32 * wave) * 32;
    ushort_t* lB = Bs + (16 * wave) * 32;

    f32x4 acc[2][4];
    #pragma unroll
    for (int i = 0; i < 2; i++)
        #pragma unroll
        for (int j = 0; j < 4; j++) acc[i][j] = (f32x4){0.f, 0.f, 0.f, 0.f};

    int wm = 32 * wave;
    int fm = lane & 15;
    int fk = (lane >> 4) * 8;

    for (int k0 = 0; k0 < K; k0 += 32) {
        __syncthreads();
        load_lds16(gA,          lA);
        load_lds16(gA + 16 * K, lA + 16 * 32);
        load_lds16(gB,          lB);
        gA += 32; gB += 32;
        __syncthreads();

        bf16x8 af[2], bfr[4];
        #pragma unroll
        for (int i = 0; i < 2; i++)
            af[i] = *(const bf16x8*)&As[(wm + 16 * i + fm) * 32 + fk];
        #pragma unroll
        for (int j = 0; j < 4; j++)
            bfr[j] = *(const bf16x8*)&Bs[(16 * j + fm) * 32 + fk];
        #pragma unroll
        for (int i = 0; i < 2; i++)
            #pragma unroll
            for (int j = 0; j < 4; j++)
                acc[i][j] = __builtin_amdgcn_mfma_f32_16x16x32_bf16(af[i], bfr[j], acc[i][j], 0, 0, 0);
    }

    int col_l = lane & 15, row_l = (lane >> 4) * 4;
    #pragma unroll
    for (int i = 0; i < 2; i++) {
        #pragma unroll
        for (int j = 0; j < 4; j++) {
            int col = n0 + 16 * j + col_l;
            float bia = bias ? bias[col] : 0.f;
            #pragma unroll
            for (int r = 0; r < 4; r++) {
                int row = m0 + wm + 16 * i + row_l + r;
                float c = acc[i][j][r] + bia;
                if (RELU) c = fmaxf(c, 0.f);
                if (resid) c += resid[(size_t)row * N + col];
                Cout[(size_t)row * N + col] = c;
            }
        }
    }
}

// ---------------- MFMA flash attention over COMPACTED keys, S^T form ----------------
// Block = (128-row Q tile, head, batch); grid 16x16x2 = 512 blocks.
// K2 [b][j][1024] compacted+zero-padded; Vt2 [b][d][j] compacted+zero-padded.
// Interior k-tiles need NO mask math; final partial tile uses index-compare bias.
__global__ __launch_bounds__(256) void fattn_mfma(const ushort_t* __restrict__ Q,
                                                  const ushort_t* __restrict__ K2,
                                                  const ushort_t* __restrict__ Vt2,
                                                  const int* __restrict__ nunb,
                                                  ushort_t* __restrict__ O) {
    __shared__ ushort_t Ks[64 * 64];    // [k][d], chunk-swizzled
    __shared__ ushort_t Vs[64 * 64];    // [d][k], chunk-swizzled
    __shared__ ushort_t Pt[128 * 68];   // [q][k], padded (+4)

    int tid = threadIdx.x, wave = tid >> 6, lane = tid & 63;
    int qt = blockIdx.x, h = blockIdx.y, b = blockIdx.z;
    int q0 = qt * 128;
    int l8 = lane >> 3, c8 = lane & 7;
    int cg = c8 ^ l8;

    const int nun = nunb[b];
    const int ntiles = (nun + 63) >> 6;

    const ushort_t* Kg = K2 + ((size_t)(b * SEQ)) * D_MODEL + h * 64;
    const ushort_t* Vg = Vt2 + ((size_t)(b * 1024 + h * 64)) * SEQ;

    int fm = lane & 15, fq = lane >> 4;
    int fk = fq * 8;
    int swz = (fm & 7) * 8;
    const float C2 = 0.18033688f;       // 0.125 * log2(e)

    // Q as B-operand fragments; wave covers q-groups {wave*16, 64+wave*16}
    bf16x8 qf[2][2];
    #pragma unroll
    for (int qg = 0; qg < 2; qg++) {
        int row = q0 + qg * 64 + wave * 16 + fm;
        const ushort_t* qr = Q + (size_t)(b * SEQ + row) * D_MODEL + h * 64;
        qf[qg][0] = *(const bf16x8*)&qr[fk];
        qf[qg][1] = *(const bf16x8*)&qr[32 + fk];
    }

    float l_acc[2] = {0.f, 0.f};        // partial denom for q = group base + fm
    f32x4 acc_o[2][4];
    #pragma unroll
    for (int qg = 0; qg < 2; qg++)
        #pragma unroll
        for (int j = 0; j < 4; j++) acc_o[qg][j] = (f32x4){0.f, 0.f, 0.f, 0.f};

    for (int kt = 0; kt < ntiles; kt++) {
        int k0 = kt * 64;
        __syncthreads();
        #pragma unroll
        for (int c = 0; c < 2; c++) {
            int row = c * 32 + wave * 8 + l8;
            load_lds16(Kg + (size_t)(k0 + row) * D_MODEL + cg * 8, &Ks[(c * 32 + wave * 8) * 64]);
            load_lds16(Vg + (size_t)row * SEQ + k0 + cg * 8,        &Vs[(c * 32 + wave * 8) * 64]);
        }
        __syncthreads();

        // ---- S^T = K Q^T ----
        f32x4 sT[2][4];
        #pragma unroll
        for (int qg = 0; qg < 2; qg++)
            #pragma unroll
            for (int jk = 0; jk < 4; jk++) sT[qg][jk] = (f32x4){0.f, 0.f, 0.f, 0.f};
        #pragma unroll
        for (int kh = 0; kh < 2; kh++) {
            bf16x8 kf[4];
            #pragma unroll
            for (int jk = 0; jk < 4; jk++)
                kf[jk] = *(const bf16x8*)&Ks[(16 * jk + fm) * 64 + ((kh * 32 + fk) ^ swz)];
            #pragma unroll
            for (int qg = 0; qg < 2; qg++)
                #pragma unroll
                for (int jk = 0; jk < 4; jk++)
                    sT[qg][jk] = __builtin_amdgcn_mfma_f32_16x16x32_bf16(kf[jk], qf[qg][kh], sT[qg][jk], 0, 0, 0);
        }

        // ---- exp2 (interior: branch-free; tail tile: index bias) ----
        if (k0 + 64 <= nun) {
            #pragma unroll
            for (int qg = 0; qg < 2; qg++)
                #pragma unroll
                for (int jk = 0; jk < 4; jk++) {
                    #pragma unroll
                    for (int r = 0; r < 4; r++) {
                        float p = exp2f(sT[qg][jk][r] * C2);
                        sT[qg][jk][r] = p;
                        l_acc[qg] += p;
                    }
                }
        } else {
            #pragma unroll
            for (int qg = 0; qg < 2; qg++)
                #pragma unroll
                for (int jk = 0; jk < 4; jk++) {
                    int kb = k0 + 16 * jk + 4 * fq;
                    #pragma unroll
                    for (int r = 0; r < 4; r++) {
                        float bias = (kb + r < nun) ? 0.f : -1000.f;
                        float p = exp2f(fmaf(sT[qg][jk][r], C2, bias));
                        sT[qg][jk][r] = p;
                        l_acc[qg] += p;
                    }
                }
        }

        // ---- packed P store: 4 consecutive keys -> b64 ----
        #pragma unroll
        for (int qg = 0; qg < 2; qg++) {
            ushort_t* prow = &Pt[(qg * 64 + wave * 16 + fm) * 68];
            #pragma unroll
            for (int jk = 0; jk < 4; jk++) {
                unsigned u0 = __float_as_uint(sT[qg][jk][0]) + 0x8000u;
                unsigned u1 = __float_as_uint(sT[qg][jk][1]) + 0x8000u;
                unsigned u2 = __float_as_uint(sT[qg][jk][2]) + 0x8000u;
                unsigned u3 = __float_as_uint(sT[qg][jk][3]) + 0x8000u;
                uint2 pk;
                pk.x = __builtin_amdgcn_perm(u1, u0, 0x07060302u);
                pk.y = __builtin_amdgcn_perm(u3, u2, 0x07060302u);
                *(uint2*)&prow[16 * jk + 4 * fq] = pk;
            }
        }
        __syncthreads();

        // ---- O += P V ----
        #pragma unroll
        for (int kh = 0; kh < 2; kh++) {
            bf16x8 vf[4];
            #pragma unroll
            for (int j = 0; j < 4; j++)
                vf[j] = *(const bf16x8*)&Vs[(16 * j + fm) * 64 + ((kh * 32 + fk) ^ swz)];
            #pragma unroll
            for (int qg = 0; qg < 2; qg++) {
                bf16x8 pf = *(const bf16x8*)&Pt[(qg * 64 + wave * 16 + fm) * 68 + kh * 32 + fk];
                #pragma unroll
                for (int j = 0; j < 4; j++)
                    acc_o[qg][j] = __builtin_amdgcn_mfma_f32_16x16x32_bf16(pf, vf[j], acc_o[qg][j], 0, 0, 0);
            }
        }
    }

    // ---- epilogue ----
    #pragma unroll
    for (int qg = 0; qg < 2; qg++) {
        float l_full = l_acc[qg];
        l_full += __shfl_xor(l_full, 16);
        l_full += __shfl_xor(l_full, 32);
        #pragma unroll
        for (int r = 0; r < 4; r++) {
            float lr = __shfl(l_full, fq * 4 + r);
            float inv = 1.0f / lr;
            int row = q0 + qg * 64 + wave * 16 + fq * 4 + r;
            #pragma unroll
            for (int j = 0; j < 4; j++) {
                int col = h * 64 + 16 * j + fm;
                O[(size_t)(b * SEQ + row) * D_MODEL + col] = f2bf(acc_o[qg][j][r] * inv);
            }
        }
    }
}

// ---------------- launch ----------------
extern "C" void kernel_launch(void* const* d_in, const int* in_sizes, int n_in,
                              void* d_out, int out_size, void* d_ws, size_t ws_size,
                              hipStream_t stream) {
    const float* x    = (const float*)d_in[0];
    const int*   mask = (const int*)  d_in[1];
    const float* wq   = (const float*)d_in[2];
    const float* wk   = (const float*)d_in[3];
    const float* wv   = (const float*)d_in[4];
    const float* wo   = (const float*)d_in[5];
    const float* w1   = (const float*)d_in[6];
    const float* b1   = (const float*)d_in[7];
    const float* w2   = (const float*)d_in[8];
    const float* b2   = (const float*)d_in[9];
    const float* ln1a = (const float*)d_in[10];
    const float* ln1b = (const float*)d_in[11];
    const float* ln2a = (const float*)d_in[12];
    const float* ln2b = (const float*)d_in[13];
    float* out = (float*)d_out;

    char* ws = (char*)d_ws;
    const size_t MB = 1024 * 1024;
    float*    x2    = (float*)   (ws + 0 * MB);    // 16 MB  (also hosts K2/Vt2 pre-WO)
    ushort_t* K2    = (ushort_t*)(ws + 0 * MB);    // 8 MB   (dead before x2 written)
    ushort_t* Vt2   = (ushort_t*)(ws + 8 * MB);    // 8 MB
    ushort_t* hbf   = (ushort_t*)(ws + 16 * MB);   // 8 MB (LN1/attn/LN2 out)
    ushort_t* qbf   = (ushort_t*)(ws + 24 * MB);   // 8 MB
    ushort_t* kbf   = (ushort_t*)(ws + 32 * MB);   // 8 MB
    ushort_t* vbf   = (ushort_t*)(ws + 40 * MB);   // 8 MB (V row-major)
    ushort_t* ffbf  = (ushort_t*)(ws + 48 * MB);   // 32 MB (FFN1 out)
    ushort_t* V2    = (ushort_t*)(ws + 48 * MB);   // 8 MB temp (dead before FFN1)
    ushort_t* wqkvt = (ushort_t*)(ws + 80 * MB);   // 6 MB
    ushort_t* wot   = (ushort_t*)(ws + 86 * MB);   // 2 MB
    ushort_t* w1t   = (ushort_t*)(ws + 88 * MB);   // 8 MB
    ushort_t* w2t   = (ushort_t*)(ws + 96 * MB);   // 8 MB
    int*      idxb  = (int*)     (ws + 104 * MB);  // 16 KB
    int*      nunb  = (int*)     (ws + 104 * MB + 64 * 1024);
    ushort_t* pbuf  = (ushort_t*)(ws + 16 * MB);   // splitk partials reuse 16-48 MB

    ushort_t* wqt = wqkvt;
    ushort_t* wkt = wqkvt + (size_t)1024 * 1024;
    ushort_t* wvt = wqkvt + (size_t)2 * 1024 * 1024;

    dim3 blk(256);

    transpose4_bf16_kernel<<<dim3(16, 16, 4), blk, 0, stream>>>(wq, wk, wv, wo, wqt, wkt, wvt, wot);
    transpose_bf16_kernel<<<dim3(64, 16), blk, 0, stream>>>(w1, w1t, D_MODEL, D_HIDDEN);
    transpose_bf16_kernel<<<dim3(16, 64), blk, 0, stream>>>(w2, w2t, D_HIDDEN, D_MODEL);
    mask_scan_kernel<<<BATCH, blk, 0, stream>>>(mask, idxb, nunb);

    ln_kernel<<<ROWS, blk, 0, stream>>>(x, ln1a, ln1b, hbf);

    // fused QKV: N = 3072, all outputs row-major bf16
    dim3 g_qkv(3 * D_MODEL / 128, ROWS / 128);
    gemm_mfma_128<false, 3><<<g_qkv, blk, 0, stream>>>(hbf, wqkvt, nullptr, nullptr,
                                                       qbf, kbf, vbf, ROWS, 3 * D_MODEL, D_MODEL);

    // compact K/V to unmasked keys (zero-padded), then transpose V
    gather_kv_kernel<<<dim3(SEQ, BATCH), blk, 0, stream>>>(kbf, vbf, idxb, nunb, K2, V2);
    transpose_v_kernel<<<dim3(D_MODEL / 64, SEQ / 64, BATCH), blk, 0, stream>>>(V2, Vt2);

    dim3 g_attn(SEQ / 128, NUM_HEADS, BATCH);
    fattn_mfma<<<g_attn, blk, 0, stream>>>(qbf, K2, Vt2, nunb, hbf);

    // x2 = x + attn @ wo
    dim3 g_wo(D_MODEL / 64, ROWS / 128);
    gemm_mfma_64<false><<<g_wo, blk, 0, stream>>>(hbf, wot, nullptr, x, x2, ROWS, D_MODEL, D_MODEL);

    ln_kernel<<<ROWS, blk, 0, stream>>>(x2, ln2a, ln2b, hbf);

    // ff = relu(h2 @ w1 + b1)
    dim3 g_ff1(D_HIDDEN / 128, ROWS / 128);
    gemm_mfma_128<true, 1><<<g_ff1, blk, 0, stream>>>(hbf, w1t, b1, nullptr, ffbf,
                                                      nullptr, nullptr, ROWS, D_HIDDEN, D_MODEL);

    // FFN2 split-K=4 + fused reduce
    dim3 g_ff2(D_MODEL / 128, ROWS / 128, 4);
    gemm_splitk<<<g_ff2, blk, 0, stream>>>(ffbf, w2t, pbuf, ROWS, D_MODEL, D_HIDDEN, 4);
    ffn2_reduce<<<ROWS, blk, 0, stream>>>(pbuf, x2, b2, out);
}

// Round 9
// 374.427 us; speedup vs baseline: 1.1027x; 1.0356x over previous
//
#include <hip/hip_runtime.h>
#include <math.h>

#define D_MODEL 1024
#define D_HIDDEN 4096
#define NUM_HEADS 16
#define D_K 64
#define EPS 1e-6f
#define MASK_FILL -1e9f
#define BATCH 2
#define SEQ 2048
#define ROWS (BATCH * SEQ)   // 4096

typedef unsigned short ushort_t;
typedef __attribute__((ext_vector_type(8))) short bf16x8;
typedef __attribute__((ext_vector_type(4))) float f32x4;

__device__ __forceinline__ unsigned short f2bf(float f) {
    union { float f; unsigned int u; } v; v.f = f;
    unsigned int r = v.u + 0x7fffu + ((v.u >> 16) & 1u);   // RNE
    return (unsigned short)(r >> 16);
}
__device__ __forceinline__ float bf2f(unsigned short u) {
    union { unsigned int u; float f; } v; v.u = ((unsigned int)u) << 16;
    return v.f;
}

__device__ __forceinline__ void load_lds16(const void* g, void* l) {
    __builtin_amdgcn_global_load_lds(
        (__attribute__((address_space(1))) void*)g,
        (__attribute__((address_space(3))) void*)l,
        16, 0, 0);
}

// ---------------- LayerNorm ----------------
__global__ __launch_bounds__(256) void ln_kernel(const float* __restrict__ x,
                                                 const float* __restrict__ a,
                                                 const float* __restrict__ b,
                                                 ushort_t* __restrict__ out) {
    int row = blockIdx.x;
    int t = threadIdx.x;
    const float* xr = x + (size_t)row * D_MODEL;

    float4 v = ((const float4*)xr)[t];
    float s  = v.x + v.y + v.z + v.w;
    float ss = v.x*v.x + v.y*v.y + v.z*v.z + v.w*v.w;
    #pragma unroll
    for (int o = 32; o > 0; o >>= 1) {
        s  += __shfl_down(s,  o);
        ss += __shfl_down(ss, o);
    }
    __shared__ float ws0[4], ws1[4];
    __shared__ float mean_s, inv_s;
    int wid = t >> 6, lane = t & 63;
    if (lane == 0) { ws0[wid] = s; ws1[wid] = ss; }
    __syncthreads();
    if (t == 0) {
        float S1 = ws0[0] + ws0[1] + ws0[2] + ws0[3];
        float S2 = ws1[0] + ws1[1] + ws1[2] + ws1[3];
        float mean = S1 / (float)D_MODEL;
        float var  = (S2 - mean * S1) / (float)(D_MODEL - 1);  // Bessel
        mean_s = mean;
        inv_s  = 1.0f / (sqrtf(var) + EPS);
    }
    __syncthreads();
    float mean = mean_s, inv = inv_s;
    float4 av = ((const float4*)a)[t];
    float4 bv = ((const float4*)b)[t];
    ushort4 o;
    o.x = f2bf(av.x * (v.x - mean) * inv + bv.x);
    o.y = f2bf(av.y * (v.y - mean) * inv + bv.y);
    o.z = f2bf(av.z * (v.z - mean) * inv + bv.z);
    o.w = f2bf(av.w * (v.w - mean) * inv + bv.w);
    *(ushort4*)&out[(size_t)row * D_MODEL + (t << 2)] = o;
}

// ---------------- weight transpose fp32->bf16: W[K][N] -> Wt[N][K] ----------------
__device__ __forceinline__ void transpose_tile(const float* W, ushort_t* Wt, int K, int N) {
    __shared__ float tile[64][65];
    int n0 = blockIdx.x * 64, k0 = blockIdx.y * 64;
    int t = threadIdx.x;
    int c4 = t & 15, r = t >> 4;
    #pragma unroll
    for (int p = 0; p < 4; p++) {
        int row = r + 16 * p;
        float4 v = *(const float4*)&W[(size_t)(k0 + row) * N + n0 + 4 * c4];
        tile[row][4*c4+0] = v.x; tile[row][4*c4+1] = v.y;
        tile[row][4*c4+2] = v.z; tile[row][4*c4+3] = v.w;
    }
    __syncthreads();
    #pragma unroll
    for (int p = 0; p < 4; p++) {
        int n = r + 16 * p;
        ushort4 o;
        o.x = f2bf(tile[4*c4+0][n]);
        o.y = f2bf(tile[4*c4+1][n]);
        o.z = f2bf(tile[4*c4+2][n]);
        o.w = f2bf(tile[4*c4+3][n]);
        *(ushort4*)&Wt[(size_t)(n0 + n) * K + k0 + 4 * c4] = o;
    }
}

__global__ __launch_bounds__(256) void transpose_bf16_kernel(const float* __restrict__ W,
                                                             ushort_t* __restrict__ Wt,
                                                             int K, int N) {
    transpose_tile(W, Wt, K, N);
}

__global__ __launch_bounds__(256) void transpose4_bf16_kernel(const float* s0, const float* s1,
                                                              const float* s2, const float* s3,
                                                              ushort_t* d0, ushort_t* d1,
                                                              ushort_t* d2, ushort_t* d3) {
    const float* S[4] = {s0, s1, s2, s3};
    ushort_t*    D[4] = {d0, d1, d2, d3};
    int z = blockIdx.z;
    transpose_tile(S[z], D[z], D_MODEL, D_MODEL);
}

// ---------------- mask prefix scan ----------------
__global__ __launch_bounds__(256) void mask_scan_kernel(const int* __restrict__ mask,
                                                        int* __restrict__ idx,
                                                        int* __restrict__ nun) {
    int b = blockIdx.x, t = threadIdx.x;
    __shared__ int sums[256];
    const int* m = mask + b * SEQ;
    int loc[8], s = 0;
    #pragma unroll
    for (int i = 0; i < 8; i++) { loc[i] = m[t * 8 + i]; s += loc[i]; }
    sums[t] = s;
    __syncthreads();
    for (int off = 1; off < 256; off <<= 1) {
        int v = sums[t];
        if (t >= off) v += sums[t - off];
        __syncthreads();
        sums[t] = v;
        __syncthreads();
    }
    int c = (t > 0) ? sums[t - 1] : 0;
    #pragma unroll
    for (int i = 0; i < 8; i++)
        if (loc[i]) { idx[b * SEQ + c] = t * 8 + i; c++; }
    if (t == 255) nun[b] = sums[255];
}

// ---------------- gather compacted K/V rows (zero-pad tail) ----------------
__global__ __launch_bounds__(256) void gather_kv_kernel(const ushort_t* __restrict__ Ksrc,
                                                        const ushort_t* __restrict__ Vsrc,
                                                        const int* __restrict__ idx,
                                                        const int* __restrict__ nun,
                                                        ushort_t* __restrict__ K2,
                                                        ushort_t* __restrict__ V2) {
    int j = blockIdx.x, b = blockIdx.y, t = threadIdx.x;
    int n = nun[b];
    size_t drow = ((size_t)b * SEQ + j) * D_MODEL;
    if (j < n) {
        size_t srow = ((size_t)b * SEQ + idx[b * SEQ + j]) * D_MODEL;
        ((ushort4*)&K2[drow])[t] = ((const ushort4*)&Ksrc[srow])[t];
        ((ushort4*)&V2[drow])[t] = ((const ushort4*)&Vsrc[srow])[t];
    } else {
        ushort4 z = {0, 0, 0, 0};
        ((ushort4*)&K2[drow])[t] = z;
        ((ushort4*)&V2[drow])[t] = z;
    }
}

// ---------------- bf16 64x64 transpose: V2[b][s][d] -> Vt2[b][d][s] ----------------
__global__ __launch_bounds__(256) void transpose_v_kernel(const ushort_t* __restrict__ V2,
                                                          ushort_t* __restrict__ Vt2) {
    __shared__ ushort_t tile[64][68];
    int n0 = blockIdx.x * 64, s0 = blockIdx.y * 64, b = blockIdx.z;
    int t = threadIdx.x;
    int c4 = t & 15, r = t >> 4;
    const ushort_t* src = V2 + (size_t)b * SEQ * D_MODEL;
    ushort_t* dst = Vt2 + (size_t)b * D_MODEL * SEQ;
    #pragma unroll
    for (int p = 0; p < 4; p++) {
        int row = r + 16 * p;
        ushort4 v = *(const ushort4*)&src[(size_t)(s0 + row) * D_MODEL + n0 + 4 * c4];
        tile[row][4*c4+0] = v.x; tile[row][4*c4+1] = v.y;
        tile[row][4*c4+2] = v.z; tile[row][4*c4+3] = v.w;
    }
    __syncthreads();
    #pragma unroll
    for (int p = 0; p < 4; p++) {
        int n = r + 16 * p;
        ushort4 o;
        o.x = tile[4*c4+0][n]; o.y = tile[4*c4+1][n];
        o.z = tile[4*c4+2][n]; o.w = tile[4*c4+3][n];
        *(ushort4*)&dst[(size_t)(n0 + n) * SEQ + s0 + 4 * c4] = o;
    }
}

// ---------------- bf16 MFMA GEMM, 128x128 tile ----------
// Grid (M/128, N/128): blockIdx.x = m-block so XCD = m%8 (A-slice L2 locality).
// LDS XOR chunk swizzle: staging reads global chunk (c^(row&3)); readers XOR back.
// OUTMODE: 0 = f32 row-major (+resid), 1 = bf16 row-major, 3 = fused QKV
template<bool RELU, int OUTMODE>
__global__ __launch_bounds__(256) void gemm_mfma_128(const ushort_t* __restrict__ A,
                                                     const ushort_t* __restrict__ Bt,
                                                     const float* __restrict__ bias,
                                                     const float* __restrict__ resid,
                                                     void* __restrict__ Cout,
                                                     ushort_t* __restrict__ outk,
                                                     ushort_t* __restrict__ outv,
                                                     int M, int N, int K) {
    __shared__ ushort_t As[128 * 32];
    __shared__ ushort_t Bs[128 * 32];

    int tid = threadIdx.x;
    int wave = tid >> 6, lane = tid & 63;
    int m0 = blockIdx.x * 128, n0 = blockIdx.y * 128;

    int srow = 32 * wave + (lane >> 2);
    int sk   = (((lane & 3) ^ ((lane >> 2) & 3)) * 8);   // XOR-swizzled source chunk
    const ushort_t* gA = A  + (size_t)(m0 + srow) * K + sk;
    const ushort_t* gB = Bt + (size_t)(n0 + srow) * K + sk;
    ushort_t* lA = As + (32 * wave) * 32;
    ushort_t* lB = Bs + (32 * wave) * 32;

    f32x4 acc[4][4];
    #pragma unroll
    for (int i = 0; i < 4; i++)
        #pragma unroll
        for (int j = 0; j < 4; j++) acc[i][j] = (f32x4){0.f, 0.f, 0.f, 0.f};

    int wm = (wave >> 1) * 64, wn = (wave & 1) * 64;
    int fm = lane & 15;
    int fk = (lane >> 4) * 8;
    int fswz = (fm & 3) * 8;            // reader-side XOR

    for (int k0 = 0; k0 < K; k0 += 32) {
        __syncthreads();
        load_lds16(gA,          lA);
        load_lds16(gA + 16 * K, lA + 16 * 32);
        load_lds16(gB,          lB);
        load_lds16(gB + 16 * K, lB + 16 * 32);
        gA += 32; gB += 32;
        __syncthreads();

        bf16x8 af[4], bfr[4];
        #pragma unroll
        for (int i = 0; i < 4; i++)
            af[i] = *(const bf16x8*)&As[(wm + 16 * i + fm) * 32 + (fk ^ fswz)];
        #pragma unroll
        for (int j = 0; j < 4; j++)
            bfr[j] = *(const bf16x8*)&Bs[(wn + 16 * j + fm) * 32 + (fk ^ fswz)];
        #pragma unroll
        for (int i = 0; i < 4; i++)
            #pragma unroll
            for (int j = 0; j < 4; j++)
                acc[i][j] = __builtin_amdgcn_mfma_f32_16x16x32_bf16(af[i], bfr[j], acc[i][j], 0, 0, 0);
    }

    int col_l = lane & 15, row_l = (lane >> 4) * 4;
    #pragma unroll
    for (int i = 0; i < 4; i++) {
        #pragma unroll
        for (int j = 0; j < 4; j++) {
            int col = n0 + wn + 16 * j + col_l;
            if (OUTMODE == 3) {
                int row = m0 + wm + 16 * i + row_l;
                ushort_t* dst;
                int c;
                if (n0 < 1024)      { dst = (ushort_t*)Cout; c = col; }
                else if (n0 < 2048) { dst = outk; c = col - 1024; }
                else                { dst = outv; c = col - 2048; }
                #pragma unroll
                for (int r = 0; r < 4; r++)
                    dst[(size_t)(row + r) * D_MODEL + c] = f2bf(acc[i][j][r]);
            } else {
                float bia = bias ? bias[col] : 0.f;
                #pragma unroll
                for (int r = 0; r < 4; r++) {
                    int row = m0 + wm + 16 * i + row_l + r;
                    float c = acc[i][j][r] + bia;
                    if (RELU) c = fmaxf(c, 0.f);
                    if (resid) c += resid[(size_t)row * N + col];
                    if (OUTMODE == 1)
                        ((ushort_t*)Cout)[(size_t)row * N + col] = f2bf(c);
                    else
                        ((float*)Cout)[(size_t)row * N + col] = c;
                }
            }
        }
    }
}

// ---------------- split-K bf16 GEMM (grid: M/128, N/128, nsplit) ----------
__global__ __launch_bounds__(256) void gemm_splitk(const ushort_t* __restrict__ A,
                                                   const ushort_t* __restrict__ Bt,
                                                   ushort_t* __restrict__ P,
                                                   int M, int N, int K, int nsplit) {
    __shared__ ushort_t As[128 * 32];
    __shared__ ushort_t Bs[128 * 32];

    int tid = threadIdx.x;
    int wave = tid >> 6, lane = tid & 63;
    int m0 = blockIdx.x * 128, n0 = blockIdx.y * 128;
    int klen = K / nsplit, kbeg = blockIdx.z * klen;

    int srow = 32 * wave + (lane >> 2);
    int sk   = (((lane & 3) ^ ((lane >> 2) & 3)) * 8);
    const ushort_t* gA = A  + (size_t)(m0 + srow) * K + kbeg + sk;
    const ushort_t* gB = Bt + (size_t)(n0 + srow) * K + kbeg + sk;
    ushort_t* lA = As + (32 * wave) * 32;
    ushort_t* lB = Bs + (32 * wave) * 32;

    f32x4 acc[4][4];
    #pragma unroll
    for (int i = 0; i < 4; i++)
        #pragma unroll
        for (int j = 0; j < 4; j++) acc[i][j] = (f32x4){0.f, 0.f, 0.f, 0.f};

    int wm = (wave >> 1) * 64, wn = (wave & 1) * 64;
    int fm = lane & 15;
    int fk = (lane >> 4) * 8;
    int fswz = (fm & 3) * 8;

    for (int k0 = 0; k0 < klen; k0 += 32) {
        __syncthreads();
        load_lds16(gA,          lA);
        load_lds16(gA + 16 * K, lA + 16 * 32);
        load_lds16(gB,          lB);
        load_lds16(gB + 16 * K, lB + 16 * 32);
        gA += 32; gB += 32;
        __syncthreads();

        bf16x8 af[4], bfr[4];
        #pragma unroll
        for (int i = 0; i < 4; i++)
            af[i] = *(const bf16x8*)&As[(wm + 16 * i + fm) * 32 + (fk ^ fswz)];
        #pragma unroll
        for (int j = 0; j < 4; j++)
            bfr[j] = *(const bf16x8*)&Bs[(wn + 16 * j + fm) * 32 + (fk ^ fswz)];
        #pragma unroll
        for (int i = 0; i < 4; i++)
            #pragma unroll
            for (int j = 0; j < 4; j++)
                acc[i][j] = __builtin_amdgcn_mfma_f32_16x16x32_bf16(af[i], bfr[j], acc[i][j], 0, 0, 0);
    }

    ushort_t* Pz = P + (size_t)blockIdx.z * M * N;
    int col_l = lane & 15, row_l = (lane >> 4) * 4;
    #pragma unroll
    for (int i = 0; i < 4; i++)
        #pragma unroll
        for (int j = 0; j < 4; j++) {
            int col = n0 + wn + 16 * j + col_l;
            #pragma unroll
            for (int r = 0; r < 4; r++) {
                int row = m0 + wm + 16 * i + row_l + r;
                Pz[(size_t)row * N + col] = f2bf(acc[i][j][r]);
            }
        }
}

// out = sum_z P[z] + x2 + b2   (2 partials)
__global__ __launch_bounds__(256) void ffn2_reduce(const ushort_t* __restrict__ P,
                                                   const float* __restrict__ x2,
                                                   const float* __restrict__ b2,
                                                   float* __restrict__ out) {
    int row = blockIdx.x, t = threadIdx.x;
    const size_t MN = (size_t)ROWS * D_MODEL;
    size_t off = (size_t)row * D_MODEL + (t << 2);
    float4 acc = *(const float4*)&x2[off];
    float4 bb  = *(const float4*)&b2[t << 2];
    acc.x += bb.x; acc.y += bb.y; acc.z += bb.z; acc.w += bb.w;
    #pragma unroll
    for (int s = 0; s < 2; s++) {
        ushort4 u = *(const ushort4*)&P[s * MN + off];
        acc.x += bf2f(u.x); acc.y += bf2f(u.y);
        acc.z += bf2f(u.z); acc.w += bf2f(u.w);
    }
    *(float4*)&out[off] = acc;
}

// ---------------- bf16 MFMA GEMM, 128x64 tile (grid: M/128, N/64) ----------
template<bool RELU>
__global__ __launch_bounds__(256) void gemm_mfma_64(const ushort_t* __restrict__ A,
                                                    const ushort_t* __restrict__ Bt,
                                                    const float* __restrict__ bias,
                                                    const float* __restrict__ resid,
                                                    float* __restrict__ Cout,
                                                    int M, int N, int K) {
    __shared__ ushort_t As[128 * 32];
    __shared__ ushort_t Bs[64 * 32];

    int tid = threadIdx.x;
    int wave = tid >> 6, lane = tid & 63;
    int m0 = blockIdx.x * 128, n0 = blockIdx.y * 64;

    int arow = 32 * wave + (lane >> 2);
    int brow = 16 * wave + (lane >> 2);
    int sk   = (((lane & 3) ^ ((lane >> 2) & 3)) * 8);
    const ushort_t* gA = A  + (size_t)(m0 + arow) * K + sk;
    const ushort_t* gB = Bt + (size_t)(n0 + brow) * K + sk;
    ushort_t* lA = As + (32 * wave) * 32;
    ushort_t* lB = Bs + (16 * wave) * 32;

    f32x4 acc[2][4];
    #pragma unroll
    for (int i = 0; i < 2; i++)
        #pragma unroll
        for (int j = 0; j < 4; j++) acc[i][j] = (f32x4){0.f, 0.f, 0.f, 0.f};

    int wm = 32 * wave;
    int fm = lane & 15;
    int fk = (lane >> 4) * 8;
    int fswz = (fm & 3) * 8;

    for (int k0 = 0; k0 < K; k0 += 32) {
        __syncthreads();
        load_lds16(gA,          lA);
        load_lds16(gA + 16 * K, lA + 16 * 32);
        load_lds16(gB,          lB);
        gA += 32; gB += 32;
        __syncthreads();

        bf16x8 af[2], bfr[4];
        #pragma unroll
        for (int i = 0; i < 2; i++)
            af[i] = *(const bf16x8*)&As[(wm + 16 * i + fm) * 32 + (fk ^ fswz)];
        #pragma unroll
        for (int j = 0; j < 4; j++)
            bfr[j] = *(const bf16x8*)&Bs[(16 * j + fm) * 32 + (fk ^ fswz)];
        #pragma unroll
        for (int i = 0; i < 2; i++)
            #pragma unroll
            for (int j = 0; j < 4; j++)
                acc[i][j] = __builtin_amdgcn_mfma_f32_16x16x32_bf16(af[i], bfr[j], acc[i][j], 0, 0, 0);
    }

    int col_l = lane & 15, row_l = (lane >> 4) * 4;
    #pragma unroll
    for (int i = 0; i < 2; i++) {
        #pragma unroll
        for (int j = 0; j < 4; j++) {
            int col = n0 + 16 * j + col_l;
            float bia = bias ? bias[col] : 0.f;
            #pragma unroll
            for (int r = 0; r < 4; r++) {
                int row = m0 + wm + 16 * i + row_l + r;
                float c = acc[i][j][r] + bia;
                if (RELU) c = fmaxf(c, 0.f);
                if (resid) c += resid[(size_t)row * N + col];
                Cout[(size_t)row * N + col] = c;
            }
        }
    }
}

// ---------------- MFMA flash attention over COMPACTED keys, S^T form ----------------
__global__ __launch_bounds__(256) void fattn_mfma(const ushort_t* __restrict__ Q,
                                                  const ushort_t* __restrict__ K2,
                                                  const ushort_t* __restrict__ Vt2,
                                                  const int* __restrict__ nunb,
                                                  ushort_t* __restrict__ O) {
    __shared__ ushort_t Ks[64 * 64];    // [k][d], chunk-swizzled
    __shared__ ushort_t Vs[64 * 64];    // [d][k], chunk-swizzled
    __shared__ ushort_t Pt[128 * 68];   // [q][k], padded (+4)

    int tid = threadIdx.x, wave = tid >> 6, lane = tid & 63;
    int qt = blockIdx.x, h = blockIdx.y, b = blockIdx.z;
    int q0 = qt * 128;
    int l8 = lane >> 3, c8 = lane & 7;
    int cg = c8 ^ l8;

    const int nun = nunb[b];
    const int ntiles = (nun + 63) >> 6;

    const ushort_t* Kg = K2 + ((size_t)(b * SEQ)) * D_MODEL + h * 64;
    const ushort_t* Vg = Vt2 + ((size_t)(b * 1024 + h * 64)) * SEQ;

    int fm = lane & 15, fq = lane >> 4;
    int fk = fq * 8;
    int swz = (fm & 7) * 8;
    const float C2 = 0.18033688f;       // 0.125 * log2(e)

    bf16x8 qf[2][2];
    #pragma unroll
    for (int qg = 0; qg < 2; qg++) {
        int row = q0 + qg * 64 + wave * 16 + fm;
        const ushort_t* qr = Q + (size_t)(b * SEQ + row) * D_MODEL + h * 64;
        qf[qg][0] = *(const bf16x8*)&qr[fk];
        qf[qg][1] = *(const bf16x8*)&qr[32 + fk];
    }

    float l_acc[2] = {0.f, 0.f};
    f32x4 acc_o[2][4];
    #pragma unroll
    for (int qg = 0; qg < 2; qg++)
        #pragma unroll
        for (int j = 0; j < 4; j++) acc_o[qg][j] = (f32x4){0.f, 0.f, 0.f, 0.f};

    for (int kt = 0; kt < ntiles; kt++) {
        int k0 = kt * 64;
        __syncthreads();
        #pragma unroll
        for (int c = 0; c < 2; c++) {
            int row = c * 32 + wave * 8 + l8;
            load_lds16(Kg + (size_t)(k0 + row) * D_MODEL + cg * 8, &Ks[(c * 32 + wave * 8) * 64]);
            load_lds16(Vg + (size_t)row * SEQ + k0 + cg * 8,        &Vs[(c * 32 + wave * 8) * 64]);
        }
        __syncthreads();

        f32x4 sT[2][4];
        #pragma unroll
        for (int qg = 0; qg < 2; qg++)
            #pragma unroll
            for (int jk = 0; jk < 4; jk++) sT[qg][jk] = (f32x4){0.f, 0.f, 0.f, 0.f};
        #pragma unroll
        for (int kh = 0; kh < 2; kh++) {
            bf16x8 kf[4];
            #pragma unroll
            for (int jk = 0; jk < 4; jk++)
                kf[jk] = *(const bf16x8*)&Ks[(16 * jk + fm) * 64 + ((kh * 32 + fk) ^ swz)];
            #pragma unroll
            for (int qg = 0; qg < 2; qg++)
                #pragma unroll
                for (int jk = 0; jk < 4; jk++)
                    sT[qg][jk] = __builtin_amdgcn_mfma_f32_16x16x32_bf16(kf[jk], qf[qg][kh], sT[qg][jk], 0, 0, 0);
        }

        if (k0 + 64 <= nun) {
            #pragma unroll
            for (int qg = 0; qg < 2; qg++)
                #pragma unroll
                for (int jk = 0; jk < 4; jk++) {
                    #pragma unroll
                    for (int r = 0; r < 4; r++) {
                        float p = exp2f(sT[qg][jk][r] * C2);
                        sT[qg][jk][r] = p;
                        l_acc[qg] += p;
                    }
                }
        } else {
            #pragma unroll
            for (int qg = 0; qg < 2; qg++)
                #pragma unroll
                for (int jk = 0; jk < 4; jk++) {
                    int kb = k0 + 16 * jk + 4 * fq;
                    #pragma unroll
                    for (int r = 0; r < 4; r++) {
                        float bias = (kb + r < nun) ? 0.f : -1000.f;
                        float p = exp2f(fmaf(sT[qg][jk][r], C2, bias));
                        sT[qg][jk][r] = p;
                        l_acc[qg] += p;
                    }
                }
        }

        #pragma unroll
        for (int qg = 0; qg < 2; qg++) {
            ushort_t* prow = &Pt[(qg * 64 + wave * 16 + fm) * 68];
            #pragma unroll
            for (int jk = 0; jk < 4; jk++) {
                unsigned u0 = __float_as_uint(sT[qg][jk][0]) + 0x8000u;
                unsigned u1 = __float_as_uint(sT[qg][jk][1]) + 0x8000u;
                unsigned u2 = __float_as_uint(sT[qg][jk][2]) + 0x8000u;
                unsigned u3 = __float_as_uint(sT[qg][jk][3]) + 0x8000u;
                uint2 pk;
                pk.x = __builtin_amdgcn_perm(u1, u0, 0x07060302u);
                pk.y = __builtin_amdgcn_perm(u3, u2, 0x07060302u);
                *(uint2*)&prow[16 * jk + 4 * fq] = pk;
            }
        }
        __syncthreads();

        #pragma unroll
        for (int kh = 0; kh < 2; kh++) {
            bf16x8 vf[4];
            #pragma unroll
            for (int j = 0; j < 4; j++)
                vf[j] = *(const bf16x8*)&Vs[(16 * j + fm) * 64 + ((kh * 32 + fk) ^ swz)];
            #pragma unroll
            for (int qg = 0; qg < 2; qg++) {
                bf16x8 pf = *(const bf16x8*)&Pt[(qg * 64 + wave * 16 + fm) * 68 + kh * 32 + fk];
                #pragma unroll
                for (int j = 0; j < 4; j++)
                    acc_o[qg][j] = __builtin_amdgcn_mfma_f32_16x16x32_bf16(pf, vf[j], acc_o[qg][j], 0, 0, 0);
            }
        }
    }

    #pragma unroll
    for (int qg = 0; qg < 2; qg++) {
        float l_full = l_acc[qg];
        l_full += __shfl_xor(l_full, 16);
        l_full += __shfl_xor(l_full, 32);
        #pragma unroll
        for (int r = 0; r < 4; r++) {
            float lr = __shfl(l_full, fq * 4 + r);
            float inv = 1.0f / lr;
            int row = q0 + qg * 64 + wave * 16 + fq * 4 + r;
            #pragma unroll
            for (int j = 0; j < 4; j++) {
                int col = h * 64 + 16 * j + fm;
                O[(size_t)(b * SEQ + row) * D_MODEL + col] = f2bf(acc_o[qg][j][r] * inv);
            }
        }
    }
}

// ---------------- launch ----------------
extern "C" void kernel_launch(void* const* d_in, const int* in_sizes, int n_in,
                              void* d_out, int out_size, void* d_ws, size_t ws_size,
                              hipStream_t stream) {
    const float* x    = (const float*)d_in[0];
    const int*   mask = (const int*)  d_in[1];
    const float* wq   = (const float*)d_in[2];
    const float* wk   = (const float*)d_in[3];
    const float* wv   = (const float*)d_in[4];
    const float* wo   = (const float*)d_in[5];
    const float* w1   = (const float*)d_in[6];
    const float* b1   = (const float*)d_in[7];
    const float* w2   = (const float*)d_in[8];
    const float* b2   = (const float*)d_in[9];
    const float* ln1a = (const float*)d_in[10];
    const float* ln1b = (const float*)d_in[11];
    const float* ln2a = (const float*)d_in[12];
    const float* ln2b = (const float*)d_in[13];
    float* out = (float*)d_out;

    char* ws = (char*)d_ws;
    const size_t MB = 1024 * 1024;
    float*    x2    = (float*)   (ws + 0 * MB);    // 16 MB (hosts K2/Vt2 pre-WO)
    ushort_t* K2    = (ushort_t*)(ws + 0 * MB);    // 8 MB
    ushort_t* Vt2   = (ushort_t*)(ws + 8 * MB);    // 8 MB
    ushort_t* hbf   = (ushort_t*)(ws + 16 * MB);   // 8 MB
    ushort_t* qbf   = (ushort_t*)(ws + 24 * MB);   // 8 MB
    ushort_t* kbf   = (ushort_t*)(ws + 32 * MB);   // 8 MB
    ushort_t* vbf   = (ushort_t*)(ws + 40 * MB);   // 8 MB
    ushort_t* ffbf  = (ushort_t*)(ws + 48 * MB);   // 32 MB (FFN1 out)
    ushort_t* V2    = (ushort_t*)(ws + 48 * MB);   // 8 MB temp (dead before FFN1)
    ushort_t* wqkvt = (ushort_t*)(ws + 80 * MB);   // 6 MB
    ushort_t* wot   = (ushort_t*)(ws + 86 * MB);   // 2 MB
    ushort_t* w1t   = (ushort_t*)(ws + 88 * MB);   // 8 MB
    ushort_t* w2t   = (ushort_t*)(ws + 96 * MB);   // 8 MB
    int*      idxb  = (int*)     (ws + 104 * MB);
    int*      nunb  = (int*)     (ws + 104 * MB + 64 * 1024);
    ushort_t* pbuf  = (ushort_t*)(ws + 16 * MB);   // 16 MB splitk partials (reuse)

    ushort_t* wqt = wqkvt;
    ushort_t* wkt = wqkvt + (size_t)1024 * 1024;
    ushort_t* wvt = wqkvt + (size_t)2 * 1024 * 1024;

    dim3 blk(256);

    transpose4_bf16_kernel<<<dim3(16, 16, 4), blk, 0, stream>>>(wq, wk, wv, wo, wqt, wkt, wvt, wot);
    transpose_bf16_kernel<<<dim3(64, 16), blk, 0, stream>>>(w1, w1t, D_MODEL, D_HIDDEN);
    transpose_bf16_kernel<<<dim3(16, 64), blk, 0, stream>>>(w2, w2t, D_HIDDEN, D_MODEL);
    mask_scan_kernel<<<BATCH, blk, 0, stream>>>(mask, idxb, nunb);

    ln_kernel<<<ROWS, blk, 0, stream>>>(x, ln1a, ln1b, hbf);

    // fused QKV: grid (m-blocks, n-blocks)
    dim3 g_qkv(ROWS / 128, 3 * D_MODEL / 128);
    gemm_mfma_128<false, 3><<<g_qkv, blk, 0, stream>>>(hbf, wqkvt, nullptr, nullptr,
                                                       qbf, kbf, vbf, ROWS, 3 * D_MODEL, D_MODEL);

    gather_kv_kernel<<<dim3(SEQ, BATCH), blk, 0, stream>>>(kbf, vbf, idxb, nunb, K2, V2);
    transpose_v_kernel<<<dim3(D_MODEL / 64, SEQ / 64, BATCH), blk, 0, stream>>>(V2, Vt2);

    dim3 g_attn(SEQ / 128, NUM_HEADS, BATCH);
    fattn_mfma<<<g_attn, blk, 0, stream>>>(qbf, K2, Vt2, nunb, hbf);

    // x2 = x + attn @ wo
    dim3 g_wo(ROWS / 128, D_MODEL / 64);
    gemm_mfma_64<false><<<g_wo, blk, 0, stream>>>(hbf, wot, nullptr, x, x2, ROWS, D_MODEL, D_MODEL);

    ln_kernel<<<ROWS, blk, 0, stream>>>(x2, ln2a, ln2b, hbf);

    // ff = relu(h2 @ w1 + b1)
    dim3 g_ff1(ROWS / 128, D_HIDDEN / 128);
    gemm_mfma_128<true, 1><<<g_ff1, blk, 0, stream>>>(hbf, w1t, b1, nullptr, ffbf,
                                                      nullptr, nullptr, ROWS, D_HIDDEN, D_MODEL);

    // FFN2 split-K=2 + fused reduce
    dim3 g_ff2(ROWS / 128, D_MODEL / 128, 2);
    gemm_splitk<<<g_ff2, blk, 0, stream>>>(ffbf, w2t, pbuf, ROWS, D_MODEL, D_HIDDEN, 2);
    ffn2_reduce<<<ROWS, blk, 0, stream>>>(pbuf, x2, b2, out);
}

// Round 10
// 365.149 us; speedup vs baseline: 1.1307x; 1.0254x over previous
//
#include <hip/hip_runtime.h>
#include <math.h>

#define D_MODEL 1024
#define D_HIDDEN 4096
#define NUM_HEADS 16
#define D_K 64
#define EPS 1e-6f
#define MASK_FILL -1e9f
#define BATCH 2
#define SEQ 2048
#define ROWS (BATCH * SEQ)   // 4096

typedef unsigned short ushort_t;
typedef __attribute__((ext_vector_type(8))) short bf16x8;
typedef __attribute__((ext_vector_type(4))) float f32x4;

__device__ __forceinline__ unsigned short f2bf(float f) {
    union { float f; unsigned int u; } v; v.f = f;
    unsigned int r = v.u + 0x7fffu + ((v.u >> 16) & 1u);   // RNE
    return (unsigned short)(r >> 16);
}
__device__ __forceinline__ float bf2f(unsigned short u) {
    union { unsigned int u; float f; } v; v.u = ((unsigned int)u) << 16;
    return v.f;
}

__device__ __forceinline__ void load_lds16(const void* g, void* l) {
    __builtin_amdgcn_global_load_lds(
        (__attribute__((address_space(1))) void*)g,
        (__attribute__((address_space(3))) void*)l,
        16, 0, 0);
}

// ---------------- LayerNorm ----------------
__global__ __launch_bounds__(256) void ln_kernel(const float* __restrict__ x,
                                                 const float* __restrict__ a,
                                                 const float* __restrict__ b,
                                                 ushort_t* __restrict__ out) {
    int row = blockIdx.x;
    int t = threadIdx.x;
    const float* xr = x + (size_t)row * D_MODEL;

    float4 v = ((const float4*)xr)[t];
    float s  = v.x + v.y + v.z + v.w;
    float ss = v.x*v.x + v.y*v.y + v.z*v.z + v.w*v.w;
    #pragma unroll
    for (int o = 32; o > 0; o >>= 1) {
        s  += __shfl_down(s,  o);
        ss += __shfl_down(ss, o);
    }
    __shared__ float ws0[4], ws1[4];
    __shared__ float mean_s, inv_s;
    int wid = t >> 6, lane = t & 63;
    if (lane == 0) { ws0[wid] = s; ws1[wid] = ss; }
    __syncthreads();
    if (t == 0) {
        float S1 = ws0[0] + ws0[1] + ws0[2] + ws0[3];
        float S2 = ws1[0] + ws1[1] + ws1[2] + ws1[3];
        float mean = S1 / (float)D_MODEL;
        float var  = (S2 - mean * S1) / (float)(D_MODEL - 1);  // Bessel
        mean_s = mean;
        inv_s  = 1.0f / (sqrtf(var) + EPS);
    }
    __syncthreads();
    float mean = mean_s, inv = inv_s;
    float4 av = ((const float4*)a)[t];
    float4 bv = ((const float4*)b)[t];
    ushort4 o;
    o.x = f2bf(av.x * (v.x - mean) * inv + bv.x);
    o.y = f2bf(av.y * (v.y - mean) * inv + bv.y);
    o.z = f2bf(av.z * (v.z - mean) * inv + bv.z);
    o.w = f2bf(av.w * (v.w - mean) * inv + bv.w);
    *(ushort4*)&out[(size_t)row * D_MODEL + (t << 2)] = o;
}

// ---------------- weight transpose fp32->bf16: W[K][N] -> Wt[N][K] ----------------
__device__ __forceinline__ void transpose_tile(const float* W, ushort_t* Wt,
                                               int K, int N, int n0, int k0) {
    __shared__ float tile[64][65];
    int t = threadIdx.x;
    int c4 = t & 15, r = t >> 4;
    #pragma unroll
    for (int p = 0; p < 4; p++) {
        int row = r + 16 * p;
        float4 v = *(const float4*)&W[(size_t)(k0 + row) * N + n0 + 4 * c4];
        tile[row][4*c4+0] = v.x; tile[row][4*c4+1] = v.y;
        tile[row][4*c4+2] = v.z; tile[row][4*c4+3] = v.w;
    }
    __syncthreads();
    #pragma unroll
    for (int p = 0; p < 4; p++) {
        int n = r + 16 * p;
        ushort4 o;
        o.x = f2bf(tile[4*c4+0][n]);
        o.y = f2bf(tile[4*c4+1][n]);
        o.z = f2bf(tile[4*c4+2][n]);
        o.w = f2bf(tile[4*c4+3][n]);
        *(ushort4*)&Wt[(size_t)(n0 + n) * K + k0 + 4 * c4] = o;
    }
}

// four 1024x1024 weights in one dispatch (grid 16x16x4)
__global__ __launch_bounds__(256) void transpose4_bf16_kernel(const float* s0, const float* s1,
                                                              const float* s2, const float* s3,
                                                              ushort_t* d0, ushort_t* d1,
                                                              ushort_t* d2, ushort_t* d3) {
    const float* S[4] = {s0, s1, s2, s3};
    ushort_t*    D[4] = {d0, d1, d2, d3};
    int z = blockIdx.z;
    transpose_tile(S[z], D[z], D_MODEL, D_MODEL, blockIdx.x * 64, blockIdx.y * 64);
}

// w1 (1024x4096) and w2 (4096x1024) in one dispatch (grid 1024x2)
__global__ __launch_bounds__(256) void transpose_ffn_kernel(const float* w1, const float* w2,
                                                            ushort_t* w1t, ushort_t* w2t) {
    int lin = blockIdx.x;
    if (blockIdx.y == 0)
        transpose_tile(w1, w1t, D_MODEL, D_HIDDEN, (lin & 63) * 64, (lin >> 6) * 64);
    else
        transpose_tile(w2, w2t, D_HIDDEN, D_MODEL, (lin & 15) * 64, (lin >> 4) * 64);
}

// ---------------- mask prefix scan ----------------
__global__ __launch_bounds__(256) void mask_scan_kernel(const int* __restrict__ mask,
                                                        int* __restrict__ idx,
                                                        int* __restrict__ nun) {
    int b = blockIdx.x, t = threadIdx.x;
    __shared__ int sums[256];
    const int* m = mask + b * SEQ;
    int loc[8], s = 0;
    #pragma unroll
    for (int i = 0; i < 8; i++) { loc[i] = m[t * 8 + i]; s += loc[i]; }
    sums[t] = s;
    __syncthreads();
    for (int off = 1; off < 256; off <<= 1) {
        int v = sums[t];
        if (t >= off) v += sums[t - off];
        __syncthreads();
        sums[t] = v;
        __syncthreads();
    }
    int c = (t > 0) ? sums[t - 1] : 0;
    #pragma unroll
    for (int i = 0; i < 8; i++)
        if (loc[i]) { idx[b * SEQ + c] = t * 8 + i; c++; }
    if (t == 255) nun[b] = sums[255];
}

// ---------------- gather compacted LN1 rows (zero-pad tail) ----------------
__global__ __launch_bounds__(256) void hgather_kernel(const ushort_t* __restrict__ h,
                                                      const int* __restrict__ idx,
                                                      const int* __restrict__ nun,
                                                      ushort_t* __restrict__ hg) {
    int j = blockIdx.x, b = blockIdx.y, t = threadIdx.x;
    size_t drow = ((size_t)b * SEQ + j) * D_MODEL;
    if (j < nun[b]) {
        size_t srow = ((size_t)(b * SEQ) + idx[b * SEQ + j]) * D_MODEL;
        ((ushort4*)&hg[drow])[t] = ((const ushort4*)&h[srow])[t];
    } else {
        ushort4 z = {0, 0, 0, 0};
        ((ushort4*)&hg[drow])[t] = z;
    }
}

// ---------------- unified QKV GEMM with compacted K/V ----------
// Grid (32, 24). y<8: Q over all 4096 rows (A=h, B=wq). y>=8: K|V over compacted
// rows per batch (A=hg[b], B=wk|wv), early-exit past ceil(nun/128)*128; epilogue
// writes K2 row-major and Vt2 transposed.
__global__ __launch_bounds__(256) void gemm_qkv(const ushort_t* __restrict__ h,
                                                const ushort_t* __restrict__ hg,
                                                const ushort_t* __restrict__ Wt,   // [3072][1024] = wq|wk|wv
                                                const int* __restrict__ nunb,
                                                ushort_t* __restrict__ Qout,
                                                ushort_t* __restrict__ K2,
                                                ushort_t* __restrict__ Vt2) {
    __shared__ ushort_t As[128 * 32];
    __shared__ ushort_t Bs[128 * 32];
    const int K = D_MODEL;

    int bx = blockIdx.x, by = blockIdx.y;
    bool isQ = (by < 8);
    int b = bx >> 4;
    int n0 = isQ ? by * 128 : (by - 8) * 128;    // within 1024 (Q) / 2048 (KV)
    const ushort_t* A;
    int m0;
    if (isQ) {
        A = h;
        m0 = bx * 128;
    } else {
        int nun = nunb[b];
        int mloc = (bx & 15) * 128;
        if (mloc >= ((nun + 127) & ~127)) return;
        A = hg + (size_t)b * SEQ * D_MODEL;
        m0 = mloc;
    }
    const ushort_t* Bt = Wt + (size_t)(isQ ? 0 : 1024) * K;

    int tid = threadIdx.x;
    int wave = tid >> 6, lane = tid & 63;

    int srow = 32 * wave + (lane >> 2);
    int sk   = (((lane & 3) ^ ((lane >> 2) & 3)) * 8);
    const ushort_t* gA = A  + (size_t)(m0 + srow) * K + sk;
    const ushort_t* gB = Bt + (size_t)(n0 + srow) * K + sk;
    ushort_t* lA = As + (32 * wave) * 32;
    ushort_t* lB = Bs + (32 * wave) * 32;

    f32x4 acc[4][4];
    #pragma unroll
    for (int i = 0; i < 4; i++)
        #pragma unroll
        for (int j = 0; j < 4; j++) acc[i][j] = (f32x4){0.f, 0.f, 0.f, 0.f};

    int wm = (wave >> 1) * 64, wn = (wave & 1) * 64;
    int fm = lane & 15;
    int fk = (lane >> 4) * 8;
    int fswz = (fm & 3) * 8;

    for (int k0 = 0; k0 < K; k0 += 32) {
        __syncthreads();
        load_lds16(gA,          lA);
        load_lds16(gA + 16 * K, lA + 16 * 32);
        load_lds16(gB,          lB);
        load_lds16(gB + 16 * K, lB + 16 * 32);
        gA += 32; gB += 32;
        __syncthreads();

        bf16x8 af[4], bfr[4];
        #pragma unroll
        for (int i = 0; i < 4; i++)
            af[i] = *(const bf16x8*)&As[(wm + 16 * i + fm) * 32 + (fk ^ fswz)];
        #pragma unroll
        for (int j = 0; j < 4; j++)
            bfr[j] = *(const bf16x8*)&Bs[(wn + 16 * j + fm) * 32 + (fk ^ fswz)];
        #pragma unroll
        for (int i = 0; i < 4; i++)
            #pragma unroll
            for (int j = 0; j < 4; j++)
                acc[i][j] = __builtin_amdgcn_mfma_f32_16x16x32_bf16(af[i], bfr[j], acc[i][j], 0, 0, 0);
    }

    int col_l = lane & 15, row_l = (lane >> 4) * 4;
    #pragma unroll
    for (int i = 0; i < 4; i++) {
        #pragma unroll
        for (int j = 0; j < 4; j++) {
            int col = n0 + wn + 16 * j + col_l;
            int row = m0 + wm + 16 * i + row_l;
            if (isQ) {
                #pragma unroll
                for (int r = 0; r < 4; r++)
                    Qout[(size_t)(row + r) * D_MODEL + col] = f2bf(acc[i][j][r]);
            } else if (col < 1024) {
                ushort_t* K2b = K2 + (size_t)b * SEQ * D_MODEL;
                #pragma unroll
                for (int r = 0; r < 4; r++)
                    K2b[(size_t)(row + r) * D_MODEL + col] = f2bf(acc[i][j][r]);
            } else {
                ushort_t* Vt2b = Vt2 + (size_t)b * D_MODEL * SEQ;
                ushort4 o;
                o.x = f2bf(acc[i][j][0]); o.y = f2bf(acc[i][j][1]);
                o.z = f2bf(acc[i][j][2]); o.w = f2bf(acc[i][j][3]);
                *(ushort4*)&Vt2b[(size_t)(col - 1024) * SEQ + row] = o;
            }
        }
    }
}

// ---------------- bf16 MFMA GEMM, 128x128 tile ----------
// OUTMODE: 0 = f32 row-major (+resid), 1 = bf16 row-major
template<bool RELU, int OUTMODE>
__global__ __launch_bounds__(256) void gemm_mfma_128(const ushort_t* __restrict__ A,
                                                     const ushort_t* __restrict__ Bt,
                                                     const float* __restrict__ bias,
                                                     const float* __restrict__ resid,
                                                     void* __restrict__ Cout,
                                                     int M, int N, int K) {
    __shared__ ushort_t As[128 * 32];
    __shared__ ushort_t Bs[128 * 32];

    int tid = threadIdx.x;
    int wave = tid >> 6, lane = tid & 63;
    int m0 = blockIdx.x * 128, n0 = blockIdx.y * 128;

    int srow = 32 * wave + (lane >> 2);
    int sk   = (((lane & 3) ^ ((lane >> 2) & 3)) * 8);
    const ushort_t* gA = A  + (size_t)(m0 + srow) * K + sk;
    const ushort_t* gB = Bt + (size_t)(n0 + srow) * K + sk;
    ushort_t* lA = As + (32 * wave) * 32;
    ushort_t* lB = Bs + (32 * wave) * 32;

    f32x4 acc[4][4];
    #pragma unroll
    for (int i = 0; i < 4; i++)
        #pragma unroll
        for (int j = 0; j < 4; j++) acc[i][j] = (f32x4){0.f, 0.f, 0.f, 0.f};

    int wm = (wave >> 1) * 64, wn = (wave & 1) * 64;
    int fm = lane & 15;
    int fk = (lane >> 4) * 8;
    int fswz = (fm & 3) * 8;

    for (int k0 = 0; k0 < K; k0 += 32) {
        __syncthreads();
        load_lds16(gA,          lA);
        load_lds16(gA + 16 * K, lA + 16 * 32);
        load_lds16(gB,          lB);
        load_lds16(gB + 16 * K, lB + 16 * 32);
        gA += 32; gB += 32;
        __syncthreads();

        bf16x8 af[4], bfr[4];
        #pragma unroll
        for (int i = 0; i < 4; i++)
            af[i] = *(const bf16x8*)&As[(wm + 16 * i + fm) * 32 + (fk ^ fswz)];
        #pragma unroll
        for (int j = 0; j < 4; j++)
            bfr[j] = *(const bf16x8*)&Bs[(wn + 16 * j + fm) * 32 + (fk ^ fswz)];
        #pragma unroll
        for (int i = 0; i < 4; i++)
            #pragma unroll
            for (int j = 0; j < 4; j++)
                acc[i][j] = __builtin_amdgcn_mfma_f32_16x16x32_bf16(af[i], bfr[j], acc[i][j], 0, 0, 0);
    }

    int col_l = lane & 15, row_l = (lane >> 4) * 4;
    #pragma unroll
    for (int i = 0; i < 4; i++) {
        #pragma unroll
        for (int j = 0; j < 4; j++) {
            int col = n0 + wn + 16 * j + col_l;
            float bia = bias ? bias[col] : 0.f;
            #pragma unroll
            for (int r = 0; r < 4; r++) {
                int row = m0 + wm + 16 * i + row_l + r;
                float c = acc[i][j][r] + bia;
                if (RELU) c = fmaxf(c, 0.f);
                if (resid) c += resid[(size_t)row * N + col];
                if (OUTMODE == 1)
                    ((ushort_t*)Cout)[(size_t)row * N + col] = f2bf(c);
                else
                    ((float*)Cout)[(size_t)row * N + col] = c;
            }
        }
    }
}

// ---------------- split-K bf16 GEMM (grid: M/128, N/128, nsplit) ----------
__global__ __launch_bounds__(256) void gemm_splitk(const ushort_t* __restrict__ A,
                                                   const ushort_t* __restrict__ Bt,
                                                   ushort_t* __restrict__ P,
                                                   int M, int N, int K, int nsplit) {
    __shared__ ushort_t As[128 * 32];
    __shared__ ushort_t Bs[128 * 32];

    int tid = threadIdx.x;
    int wave = tid >> 6, lane = tid & 63;
    int m0 = blockIdx.x * 128, n0 = blockIdx.y * 128;
    int klen = K / nsplit, kbeg = blockIdx.z * klen;

    int srow = 32 * wave + (lane >> 2);
    int sk   = (((lane & 3) ^ ((lane >> 2) & 3)) * 8);
    const ushort_t* gA = A  + (size_t)(m0 + srow) * K + kbeg + sk;
    const ushort_t* gB = Bt + (size_t)(n0 + srow) * K + kbeg + sk;
    ushort_t* lA = As + (32 * wave) * 32;
    ushort_t* lB = Bs + (32 * wave) * 32;

    f32x4 acc[4][4];
    #pragma unroll
    for (int i = 0; i < 4; i++)
        #pragma unroll
        for (int j = 0; j < 4; j++) acc[i][j] = (f32x4){0.f, 0.f, 0.f, 0.f};

    int wm = (wave >> 1) * 64, wn = (wave & 1) * 64;
    int fm = lane & 15;
    int fk = (lane >> 4) * 8;
    int fswz = (fm & 3) * 8;

    for (int k0 = 0; k0 < klen; k0 += 32) {
        __syncthreads();
        load_lds16(gA,          lA);
        load_lds16(gA + 16 * K, lA + 16 * 32);
        load_lds16(gB,          lB);
        load_lds16(gB + 16 * K, lB + 16 * 32);
        gA += 32; gB += 32;
        __syncthreads();

        bf16x8 af[4], bfr[4];
        #pragma unroll
        for (int i = 0; i < 4; i++)
            af[i] = *(const bf16x8*)&As[(wm + 16 * i + fm) * 32 + (fk ^ fswz)];
        #pragma unroll
        for (int j = 0; j < 4; j++)
            bfr[j] = *(const bf16x8*)&Bs[(wn + 16 * j + fm) * 32 + (fk ^ fswz)];
        #pragma unroll
        for (int i = 0; i < 4; i++)
            #pragma unroll
            for (int j = 0; j < 4; j++)
                acc[i][j] = __builtin_amdgcn_mfma_f32_16x16x32_bf16(af[i], bfr[j], acc[i][j], 0, 0, 0);
    }

    ushort_t* Pz = P + (size_t)blockIdx.z * M * N;
    int col_l = lane & 15, row_l = (lane >> 4) * 4;
    #pragma unroll
    for (int i = 0; i < 4; i++)
        #pragma unroll
        for (int j = 0; j < 4; j++) {
            int col = n0 + wn + 16 * j + col_l;
            #pragma unroll
            for (int r = 0; r < 4; r++) {
                int row = m0 + wm + 16 * i + row_l + r;
                Pz[(size_t)row * N + col] = f2bf(acc[i][j][r]);
            }
        }
}

// out = sum_z P[z] + x2 + b2   (2 partials)
__global__ __launch_bounds__(256) void ffn2_reduce(const ushort_t* __restrict__ P,
                                                   const float* __restrict__ x2,
                                                   const float* __restrict__ b2,
                                                   float* __restrict__ out) {
    int row = blockIdx.x, t = threadIdx.x;
    const size_t MN = (size_t)ROWS * D_MODEL;
    size_t off = (size_t)row * D_MODEL + (t << 2);
    float4 acc = *(const float4*)&x2[off];
    float4 bb  = *(const float4*)&b2[t << 2];
    acc.x += bb.x; acc.y += bb.y; acc.z += bb.z; acc.w += bb.w;
    #pragma unroll
    for (int s = 0; s < 2; s++) {
        ushort4 u = *(const ushort4*)&P[s * MN + off];
        acc.x += bf2f(u.x); acc.y += bf2f(u.y);
        acc.z += bf2f(u.z); acc.w += bf2f(u.w);
    }
    *(float4*)&out[off] = acc;
}

// ---------------- bf16 MFMA GEMM, 128x64 tile (grid: M/128, N/64) ----------
template<bool RELU>
__global__ __launch_bounds__(256) void gemm_mfma_64(const ushort_t* __restrict__ A,
                                                    const ushort_t* __restrict__ Bt,
                                                    const float* __restrict__ bias,
                                                    const float* __restrict__ resid,
                                                    float* __restrict__ Cout,
                                                    int M, int N, int K) {
    __shared__ ushort_t As[128 * 32];
    __shared__ ushort_t Bs[64 * 32];

    int tid = threadIdx.x;
    int wave = tid >> 6, lane = tid & 63;
    int m0 = blockIdx.x * 128, n0 = blockIdx.y * 64;

    int arow = 32 * wave + (lane >> 2);
    int brow = 16 * wave + (lane >> 2);
    int sk   = (((lane & 3) ^ ((lane >> 2) & 3)) * 8);
    const ushort_t* gA = A  + (size_t)(m0 + arow) * K + sk;
    const ushort_t* gB = Bt + (size_t)(n0 + brow) * K + sk;
    ushort_t* lA = As + (32 * wave) * 32;
    ushort_t* lB = Bs + (16 * wave) * 32;

    f32x4 acc[2][4];
    #pragma unroll
    for (int i = 0; i < 2; i++)
        #pragma unroll
        for (int j = 0; j < 4; j++) acc[i][j] = (f32x4){0.f, 0.f, 0.f, 0.f};

    int wm = 32 * wave;
    int fm = lane & 15;
    int fk = (lane >> 4) * 8;
    int fswz = (fm & 3) * 8;

    for (int k0 = 0; k0 < K; k0 += 32) {
        __syncthreads();
        load_lds16(gA,          lA);
        load_lds16(gA + 16 * K, lA + 16 * 32);
        load_lds16(gB,          lB);
        gA += 32; gB += 32;
        __syncthreads();

        bf16x8 af[2], bfr[4];
        #pragma unroll
        for (int i = 0; i < 2; i++)
            af[i] = *(const bf16x8*)&As[(wm + 16 * i + fm) * 32 + (fk ^ fswz)];
        #pragma unroll
        for (int j = 0; j < 4; j++)
            bfr[j] = *(const bf16x8*)&Bs[(16 * j + fm) * 32 + (fk ^ fswz)];
        #pragma unroll
        for (int i = 0; i < 2; i++)
            #pragma unroll
            for (int j = 0; j < 4; j++)
                acc[i][j] = __builtin_amdgcn_mfma_f32_16x16x32_bf16(af[i], bfr[j], acc[i][j], 0, 0, 0);
    }

    int col_l = lane & 15, row_l = (lane >> 4) * 4;
    #pragma unroll
    for (int i = 0; i < 2; i++) {
        #pragma unroll
        for (int j = 0; j < 4; j++) {
            int col = n0 + 16 * j + col_l;
            float bia = bias ? bias[col] : 0.f;
            #pragma unroll
            for (int r = 0; r < 4; r++) {
                int row = m0 + wm + 16 * i + row_l + r;
                float c = acc[i][j][r] + bia;
                if (RELU) c = fmaxf(c, 0.f);
                if (resid) c += resid[(size_t)row * N + col];
                Cout[(size_t)row * N + col] = c;
            }
        }
    }
}

// ---------------- MFMA flash attention over COMPACTED keys, S^T form ----------------
__global__ __launch_bounds__(256) void fattn_mfma(const ushort_t* __restrict__ Q,
                                                  const ushort_t* __restrict__ K2,
                                                  const ushort_t* __restrict__ Vt2,
                                                  const int* __restrict__ nunb,
                                                  ushort_t* __restrict__ O) {
    __shared__ ushort_t Ks[64 * 64];    // [k][d], chunk-swizzled
    __shared__ ushort_t Vs[64 * 64];    // [d][k], chunk-swizzled
    __shared__ ushort_t Pt[128 * 68];   // [q][k], padded (+4)

    int tid = threadIdx.x, wave = tid >> 6, lane = tid & 63;
    int qt = blockIdx.x, h = blockIdx.y, b = blockIdx.z;
    int q0 = qt * 128;
    int l8 = lane >> 3, c8 = lane & 7;
    int cg = c8 ^ l8;

    const int nun = nunb[b];
    const int ntiles = (nun + 63) >> 6;

    const ushort_t* Kg = K2 + ((size_t)(b * SEQ)) * D_MODEL + h * 64;
    const ushort_t* Vg = Vt2 + ((size_t)(b * 1024 + h * 64)) * SEQ;

    int fm = lane & 15, fq = lane >> 4;
    int fk = fq * 8;
    int swz = (fm & 7) * 8;
    const float C2 = 0.18033688f;       // 0.125 * log2(e)

    bf16x8 qf[2][2];
    #pragma unroll
    for (int qg = 0; qg < 2; qg++) {
        int row = q0 + qg * 64 + wave * 16 + fm;
        const ushort_t* qr = Q + (size_t)(b * SEQ + row) * D_MODEL + h * 64;
        qf[qg][0] = *(const bf16x8*)&qr[fk];
        qf[qg][1] = *(const bf16x8*)&qr[32 + fk];
    }

    float l_acc[2] = {0.f, 0.f};
    f32x4 acc_o[2][4];
    #pragma unroll
    for (int qg = 0; qg < 2; qg++)
        #pragma unroll
        for (int j = 0; j < 4; j++) acc_o[qg][j] = (f32x4){0.f, 0.f, 0.f, 0.f};

    for (int kt = 0; kt < ntiles; kt++) {
        int k0 = kt * 64;
        __syncthreads();
        #pragma unroll
        for (int c = 0; c < 2; c++) {
            int row = c * 32 + wave * 8 + l8;
            load_lds16(Kg + (size_t)(k0 + row) * D_MODEL + cg * 8, &Ks[(c * 32 + wave * 8) * 64]);
            load_lds16(Vg + (size_t)row * SEQ + k0 + cg * 8,        &Vs[(c * 32 + wave * 8) * 64]);
        }
        __syncthreads();

        f32x4 sT[2][4];
        #pragma unroll
        for (int qg = 0; qg < 2; qg++)
            #pragma unroll
            for (int jk = 0; jk < 4; jk++) sT[qg][jk] = (f32x4){0.f, 0.f, 0.f, 0.f};
        #pragma unroll
        for (int kh = 0; kh < 2; kh++) {
            bf16x8 kf[4];
            #pragma unroll
            for (int jk = 0; jk < 4; jk++)
                kf[jk] = *(const bf16x8*)&Ks[(16 * jk + fm) * 64 + ((kh * 32 + fk) ^ swz)];
            #pragma unroll
            for (int qg = 0; qg < 2; qg++)
                #pragma unroll
                for (int jk = 0; jk < 4; jk++)
                    sT[qg][jk] = __builtin_amdgcn_mfma_f32_16x16x32_bf16(kf[jk], qf[qg][kh], sT[qg][jk], 0, 0, 0);
        }

        if (k0 + 64 <= nun) {
            #pragma unroll
            for (int qg = 0; qg < 2; qg++)
                #pragma unroll
                for (int jk = 0; jk < 4; jk++) {
                    #pragma unroll
                    for (int r = 0; r < 4; r++) {
                        float p = exp2f(sT[qg][jk][r] * C2);
                        sT[qg][jk][r] = p;
                        l_acc[qg] += p;
                    }
                }
        } else {
            #pragma unroll
            for (int qg = 0; qg < 2; qg++)
                #pragma unroll
                for (int jk = 0; jk < 4; jk++) {
                    int kb = k0 + 16 * jk + 4 * fq;
                    #pragma unroll
                    for (int r = 0; r < 4; r++) {
                        float bias = (kb + r < nun) ? 0.f : -1000.f;
                        float p = exp2f(fmaf(sT[qg][jk][r], C2, bias));
                        sT[qg][jk][r] = p;
                        l_acc[qg] += p;
                    }
                }
        }

        #pragma unroll
        for (int qg = 0; qg < 2; qg++) {
            ushort_t* prow = &Pt[(qg * 64 + wave * 16 + fm) * 68];
            #pragma unroll
            for (int jk = 0; jk < 4; jk++) {
                unsigned u0 = __float_as_uint(sT[qg][jk][0]) + 0x8000u;
                unsigned u1 = __float_as_uint(sT[qg][jk][1]) + 0x8000u;
                unsigned u2 = __float_as_uint(sT[qg][jk][2]) + 0x8000u;
                unsigned u3 = __float_as_uint(sT[qg][jk][3]) + 0x8000u;
                uint2 pk;
                pk.x = __builtin_amdgcn_perm(u1, u0, 0x07060302u);
                pk.y = __builtin_amdgcn_perm(u3, u2, 0x07060302u);
                *(uint2*)&prow[16 * jk + 4 * fq] = pk;
            }
        }
        __syncthreads();

        #pragma unroll
        for (int kh = 0; kh < 2; kh++) {
            bf16x8 vf[4];
            #pragma unroll
            for (int j = 0; j < 4; j++)
                vf[j] = *(const bf16x8*)&Vs[(16 * j + fm) * 64 + ((kh * 32 + fk) ^ swz)];
            #pragma unroll
            for (int qg = 0; qg < 2; qg++) {
                bf16x8 pf = *(const bf16x8*)&Pt[(qg * 64 + wave * 16 + fm) * 68 + kh * 32 + fk];
                #pragma unroll
                for (int j = 0; j < 4; j++)
                    acc_o[qg][j] = __builtin_amdgcn_mfma_f32_16x16x32_bf16(pf, vf[j], acc_o[qg][j], 0, 0, 0);
            }
        }
    }

    #pragma unroll
    for (int qg = 0; qg < 2; qg++) {
        float l_full = l_acc[qg];
        l_full += __shfl_xor(l_full, 16);
        l_full += __shfl_xor(l_full, 32);
        #pragma unroll
        for (int r = 0; r < 4; r++) {
            float lr = __shfl(l_full, fq * 4 + r);
            float inv = 1.0f / lr;
            int row = q0 + qg * 64 + wave * 16 + fq * 4 + r;
            #pragma unroll
            for (int j = 0; j < 4; j++) {
                int col = h * 64 + 16 * j + fm;
                O[(size_t)(b * SEQ + row) * D_MODEL + col] = f2bf(acc_o[qg][j][r] * inv);
            }
        }
    }
}

// ---------------- launch ----------------
extern "C" void kernel_launch(void* const* d_in, const int* in_sizes, int n_in,
                              void* d_out, int out_size, void* d_ws, size_t ws_size,
                              hipStream_t stream) {
    const float* x    = (const float*)d_in[0];
    const int*   mask = (const int*)  d_in[1];
    const float* wq   = (const float*)d_in[2];
    const float* wk   = (const float*)d_in[3];
    const float* wv   = (const float*)d_in[4];
    const float* wo   = (const float*)d_in[5];
    const float* w1   = (const float*)d_in[6];
    const float* b1   = (const float*)d_in[7];
    const float* w2   = (const float*)d_in[8];
    const float* b2   = (const float*)d_in[9];
    const float* ln1a = (const float*)d_in[10];
    const float* ln1b = (const float*)d_in[11];
    const float* ln2a = (const float*)d_in[12];
    const float* ln2b = (const float*)d_in[13];
    float* out = (float*)d_out;

    char* ws = (char*)d_ws;
    const size_t MB = 1024 * 1024;
    float*    x2    = (float*)   (ws + 0 * MB);    // 16 MB (hosts K2/Vt2 pre-WO)
    ushort_t* K2    = (ushort_t*)(ws + 0 * MB);    // 8 MB  (dead before x2 written)
    ushort_t* Vt2   = (ushort_t*)(ws + 8 * MB);    // 8 MB
    ushort_t* hbf   = (ushort_t*)(ws + 16 * MB);   // 8 MB (LN1/attn/LN2 out)
    ushort_t* qbf   = (ushort_t*)(ws + 24 * MB);   // 8 MB
    ushort_t* hg    = (ushort_t*)(ws + 40 * MB);   // 8 MB (compacted LN1 rows)
    ushort_t* ffbf  = (ushort_t*)(ws + 48 * MB);   // 32 MB (FFN1 out)
    ushort_t* wqkvt = (ushort_t*)(ws + 80 * MB);   // 6 MB: wq|wk|wv transposed
    ushort_t* wot   = (ushort_t*)(ws + 86 * MB);   // 2 MB
    ushort_t* w1t   = (ushort_t*)(ws + 88 * MB);   // 8 MB
    ushort_t* w2t   = (ushort_t*)(ws + 96 * MB);   // 8 MB
    int*      idxb  = (int*)     (ws + 104 * MB);
    int*      nunb  = (int*)     (ws + 104 * MB + 64 * 1024);
    ushort_t* pbuf  = (ushort_t*)(ws + 16 * MB);   // 16 MB splitk partials (reuse)

    ushort_t* wqt = wqkvt;
    ushort_t* wkt = wqkvt + (size_t)1024 * 1024;
    ushort_t* wvt = wqkvt + (size_t)2 * 1024 * 1024;

    dim3 blk(256);

    transpose4_bf16_kernel<<<dim3(16, 16, 4), blk, 0, stream>>>(wq, wk, wv, wo, wqt, wkt, wvt, wot);
    transpose_ffn_kernel<<<dim3(1024, 2), blk, 0, stream>>>(w1, w2, w1t, w2t);
    mask_scan_kernel<<<BATCH, blk, 0, stream>>>(mask, idxb, nunb);

    ln_kernel<<<ROWS, blk, 0, stream>>>(x, ln1a, ln1b, hbf);

    // compact LN1 rows for the K/V GEMM
    hgather_kernel<<<dim3(SEQ, BATCH), blk, 0, stream>>>(hbf, idxb, nunb, hg);

    // unified QKV: Q over all rows; K/V over compacted rows, V written transposed
    gemm_qkv<<<dim3(32, 24), blk, 0, stream>>>(hbf, hg, wqkvt, nunb, qbf, K2, Vt2);

    dim3 g_attn(SEQ / 128, NUM_HEADS, BATCH);
    fattn_mfma<<<g_attn, blk, 0, stream>>>(qbf, K2, Vt2, nunb, hbf);

    // x2 = x + attn @ wo
    dim3 g_wo(ROWS / 128, D_MODEL / 64);
    gemm_mfma_64<false><<<g_wo, blk, 0, stream>>>(hbf, wot, nullptr, x, x2, ROWS, D_MODEL, D_MODEL);

    ln_kernel<<<ROWS, blk, 0, stream>>>(x2, ln2a, ln2b, hbf);

    // ff = relu(h2 @ w1 + b1)
    dim3 g_ff1(ROWS / 128, D_HIDDEN / 128);
    gemm_mfma_128<true, 1><<<g_ff1, blk, 0, stream>>>(hbf, w1t, b1, nullptr, ffbf,
                                                      ROWS, D_HIDDEN, D_MODEL);

    // FFN2 split-K=2 + fused reduce
    dim3 g_ff2(ROWS / 128, D_MODEL / 128, 2);
    gemm_splitk<<<g_ff2, blk, 0, stream>>>(ffbf, w2t, pbuf, ROWS, D_MODEL, D_HIDDEN, 2);
    ffn2_reduce<<<ROWS, blk, 0, stream>>>(pbuf, x2, b2, out);
}

// Round 11
// 348.212 us; speedup vs baseline: 1.1857x; 1.0486x over previous
//
#include <hip/hip_runtime.h>
#include <math.h>

#define D_MODEL 1024
#define D_HIDDEN 4096
#define NUM_HEADS 16
#define D_K 64
#define EPS 1e-6f
#define MASK_FILL -1e9f
#define BATCH 2
#define SEQ 2048
#define ROWS (BATCH * SEQ)   // 4096

typedef unsigned short ushort_t;
typedef __attribute__((ext_vector_type(8))) short bf16x8;
typedef __attribute__((ext_vector_type(4))) float f32x4;

__device__ __forceinline__ unsigned short f2bf(float f) {
    union { float f; unsigned int u; } v; v.f = f;
    unsigned int r = v.u + 0x7fffu + ((v.u >> 16) & 1u);   // RNE
    return (unsigned short)(r >> 16);
}
__device__ __forceinline__ float bf2f(unsigned short u) {
    union { unsigned int u; float f; } v; v.u = ((unsigned int)u) << 16;
    return v.f;
}

__device__ __forceinline__ void load_lds16(const void* g, void* l) {
    __builtin_amdgcn_global_load_lds(
        (__attribute__((address_space(1))) void*)g,
        (__attribute__((address_space(3))) void*)l,
        16, 0, 0);
}

// ---------------- LayerNorm ----------------
__global__ __launch_bounds__(256) void ln_kernel(const float* __restrict__ x,
                                                 const float* __restrict__ a,
                                                 const float* __restrict__ b,
                                                 ushort_t* __restrict__ out) {
    int row = blockIdx.x;
    int t = threadIdx.x;
    const float* xr = x + (size_t)row * D_MODEL;

    float4 v = ((const float4*)xr)[t];
    float s  = v.x + v.y + v.z + v.w;
    float ss = v.x*v.x + v.y*v.y + v.z*v.z + v.w*v.w;
    #pragma unroll
    for (int o = 32; o > 0; o >>= 1) {
        s  += __shfl_down(s,  o);
        ss += __shfl_down(ss, o);
    }
    __shared__ float ws0[4], ws1[4];
    __shared__ float mean_s, inv_s;
    int wid = t >> 6, lane = t & 63;
    if (lane == 0) { ws0[wid] = s; ws1[wid] = ss; }
    __syncthreads();
    if (t == 0) {
        float S1 = ws0[0] + ws0[1] + ws0[2] + ws0[3];
        float S2 = ws1[0] + ws1[1] + ws1[2] + ws1[3];
        float mean = S1 / (float)D_MODEL;
        float var  = (S2 - mean * S1) / (float)(D_MODEL - 1);  // Bessel
        mean_s = mean;
        inv_s  = 1.0f / (sqrtf(var) + EPS);
    }
    __syncthreads();
    float mean = mean_s, inv = inv_s;
    float4 av = ((const float4*)a)[t];
    float4 bv = ((const float4*)b)[t];
    ushort4 o;
    o.x = f2bf(av.x * (v.x - mean) * inv + bv.x);
    o.y = f2bf(av.y * (v.y - mean) * inv + bv.y);
    o.z = f2bf(av.z * (v.z - mean) * inv + bv.z);
    o.w = f2bf(av.w * (v.w - mean) * inv + bv.w);
    *(ushort4*)&out[(size_t)row * D_MODEL + (t << 2)] = o;
}

// ---------------- weight transpose fp32->bf16: W[K][N] -> Wt[N][K] ----------------
__device__ __forceinline__ void transpose_tile(const float* W, ushort_t* Wt,
                                               int K, int N, int n0, int k0) {
    __shared__ float tile[64][65];
    int t = threadIdx.x;
    int c4 = t & 15, r = t >> 4;
    #pragma unroll
    for (int p = 0; p < 4; p++) {
        int row = r + 16 * p;
        float4 v = *(const float4*)&W[(size_t)(k0 + row) * N + n0 + 4 * c4];
        tile[row][4*c4+0] = v.x; tile[row][4*c4+1] = v.y;
        tile[row][4*c4+2] = v.z; tile[row][4*c4+3] = v.w;
    }
    __syncthreads();
    #pragma unroll
    for (int p = 0; p < 4; p++) {
        int n = r + 16 * p;
        ushort4 o;
        o.x = f2bf(tile[4*c4+0][n]);
        o.y = f2bf(tile[4*c4+1][n]);
        o.z = f2bf(tile[4*c4+2][n]);
        o.w = f2bf(tile[4*c4+3][n]);
        *(ushort4*)&Wt[(size_t)(n0 + n) * K + k0 + 4 * c4] = o;
    }
}

__global__ __launch_bounds__(256) void transpose4_bf16_kernel(const float* s0, const float* s1,
                                                              const float* s2, const float* s3,
                                                              ushort_t* d0, ushort_t* d1,
                                                              ushort_t* d2, ushort_t* d3) {
    const float* S[4] = {s0, s1, s2, s3};
    ushort_t*    D[4] = {d0, d1, d2, d3};
    int z = blockIdx.z;
    transpose_tile(S[z], D[z], D_MODEL, D_MODEL, blockIdx.x * 64, blockIdx.y * 64);
}

__global__ __launch_bounds__(256) void transpose_ffn_kernel(const float* w1, const float* w2,
                                                            ushort_t* w1t, ushort_t* w2t) {
    int lin = blockIdx.x;
    if (blockIdx.y == 0)
        transpose_tile(w1, w1t, D_MODEL, D_HIDDEN, (lin & 63) * 64, (lin >> 6) * 64);
    else
        transpose_tile(w2, w2t, D_HIDDEN, D_MODEL, (lin & 15) * 64, (lin >> 4) * 64);
}

// ---------------- mask prefix scan ----------------
__global__ __launch_bounds__(256) void mask_scan_kernel(const int* __restrict__ mask,
                                                        int* __restrict__ idx,
                                                        int* __restrict__ nun) {
    int b = blockIdx.x, t = threadIdx.x;
    __shared__ int sums[256];
    const int* m = mask + b * SEQ;
    int loc[8], s = 0;
    #pragma unroll
    for (int i = 0; i < 8; i++) { loc[i] = m[t * 8 + i]; s += loc[i]; }
    sums[t] = s;
    __syncthreads();
    for (int off = 1; off < 256; off <<= 1) {
        int v = sums[t];
        if (t >= off) v += sums[t - off];
        __syncthreads();
        sums[t] = v;
        __syncthreads();
    }
    int c = (t > 0) ? sums[t - 1] : 0;
    #pragma unroll
    for (int i = 0; i < 8; i++)
        if (loc[i]) { idx[b * SEQ + c] = t * 8 + i; c++; }
    if (t == 255) nun[b] = sums[255];
}

// ---------------- gather compacted LN1 rows (zero-pad tail) ----------------
__global__ __launch_bounds__(256) void hgather_kernel(const ushort_t* __restrict__ h,
                                                      const int* __restrict__ idx,
                                                      const int* __restrict__ nun,
                                                      ushort_t* __restrict__ hg) {
    int j = blockIdx.x, b = blockIdx.y, t = threadIdx.x;
    size_t drow = ((size_t)b * SEQ + j) * D_MODEL;
    if (j < nun[b]) {
        size_t srow = ((size_t)(b * SEQ) + idx[b * SEQ + j]) * D_MODEL;
        ((ushort4*)&hg[drow])[t] = ((const ushort4*)&h[srow])[t];
    } else {
        ushort4 z = {0, 0, 0, 0};
        ((ushort4*)&hg[drow])[t] = z;
    }
}

// ======== BK=64 staging/read pattern (fattn-style, 128B LDS rows, XOR swizzle) =====
// Stage: wave stages 32 rows per tile; lane l -> row sub l>>3, global chunk (l&7)^(l>>3).
// Read: row r chunk c lives at LDS chunk c ^ (r&7)  -> 2-way max, conflict-free.

// ---------------- unified QKV GEMM with compacted K/V ----------
__global__ __launch_bounds__(256) void gemm_qkv(const ushort_t* __restrict__ h,
                                                const ushort_t* __restrict__ hg,
                                                const ushort_t* __restrict__ Wt,   // [3072][1024]
                                                const int* __restrict__ nunb,
                                                ushort_t* __restrict__ Qout,
                                                ushort_t* __restrict__ K2,
                                                ushort_t* __restrict__ Vt2) {
    __shared__ ushort_t As[128 * 64];
    __shared__ ushort_t Bs[128 * 64];
    const int K = D_MODEL;

    int bx = blockIdx.x, by = blockIdx.y;
    bool isQ = (by < 8);
    int b = bx >> 4;
    int n0 = isQ ? by * 128 : (by - 8) * 128;
    const ushort_t* A;
    int m0;
    if (isQ) {
        A = h;
        m0 = bx * 128;
    } else {
        int nun = nunb[b];
        int mloc = (bx & 15) * 128;
        if (mloc >= ((nun + 127) & ~127)) return;
        A = hg + (size_t)b * SEQ * D_MODEL;
        m0 = mloc;
    }
    const ushort_t* Bt = Wt + (size_t)(isQ ? 0 : 1024) * K;

    int tid = threadIdx.x;
    int wave = tid >> 6, lane = tid & 63;
    int l8 = lane >> 3, c8 = lane & 7;
    int cg = c8 ^ l8;

    const ushort_t* gA = A  + (size_t)(m0 + 32 * wave + l8) * K + cg * 8;
    const ushort_t* gB = Bt + (size_t)(n0 + 32 * wave + l8) * K + cg * 8;
    ushort_t* lA = As + (32 * wave) * 64;
    ushort_t* lB = Bs + (32 * wave) * 64;

    f32x4 acc[4][4];
    #pragma unroll
    for (int i = 0; i < 4; i++)
        #pragma unroll
        for (int j = 0; j < 4; j++) acc[i][j] = (f32x4){0.f, 0.f, 0.f, 0.f};

    int wm = (wave >> 1) * 64, wn = (wave & 1) * 64;
    int fm = lane & 15;
    int fk = (lane >> 4) * 8;
    int swz = (fm & 7) * 8;

    for (int k0 = 0; k0 < K; k0 += 64) {
        __syncthreads();
        #pragma unroll
        for (int c = 0; c < 4; c++) {
            load_lds16(gA + (size_t)(8 * c) * K, lA + (8 * c) * 64);
            load_lds16(gB + (size_t)(8 * c) * K, lB + (8 * c) * 64);
        }
        gA += 64; gB += 64;
        __syncthreads();

        #pragma unroll
        for (int kh = 0; kh < 2; kh++) {
            int kk = kh * 32;
            bf16x8 af[4], bfr[4];
            #pragma unroll
            for (int i = 0; i < 4; i++)
                af[i] = *(const bf16x8*)&As[(wm + 16 * i + fm) * 64 + ((kk + fk) ^ swz)];
            #pragma unroll
            for (int j = 0; j < 4; j++)
                bfr[j] = *(const bf16x8*)&Bs[(wn + 16 * j + fm) * 64 + ((kk + fk) ^ swz)];
            #pragma unroll
            for (int i = 0; i < 4; i++)
                #pragma unroll
                for (int j = 0; j < 4; j++)
                    acc[i][j] = __builtin_amdgcn_mfma_f32_16x16x32_bf16(af[i], bfr[j], acc[i][j], 0, 0, 0);
        }
    }

    int col_l = lane & 15, row_l = (lane >> 4) * 4;
    #pragma unroll
    for (int i = 0; i < 4; i++) {
        #pragma unroll
        for (int j = 0; j < 4; j++) {
            int col = n0 + wn + 16 * j + col_l;
            int row = m0 + wm + 16 * i + row_l;
            if (isQ) {
                #pragma unroll
                for (int r = 0; r < 4; r++)
                    Qout[(size_t)(row + r) * D_MODEL + col] = f2bf(acc[i][j][r]);
            } else if (col < 1024) {
                ushort_t* K2b = K2 + (size_t)b * SEQ * D_MODEL;
                #pragma unroll
                for (int r = 0; r < 4; r++)
                    K2b[(size_t)(row + r) * D_MODEL + col] = f2bf(acc[i][j][r]);
            } else {
                ushort_t* Vt2b = Vt2 + (size_t)b * D_MODEL * SEQ;
                ushort4 o;
                o.x = f2bf(acc[i][j][0]); o.y = f2bf(acc[i][j][1]);
                o.z = f2bf(acc[i][j][2]); o.w = f2bf(acc[i][j][3]);
                *(ushort4*)&Vt2b[(size_t)(col - 1024) * SEQ + row] = o;
            }
        }
    }
}

// ---------------- bf16 MFMA GEMM, 128x128 tile, BK=64 ----------
template<bool RELU, int OUTMODE>
__global__ __launch_bounds__(256) void gemm_mfma_128(const ushort_t* __restrict__ A,
                                                     const ushort_t* __restrict__ Bt,
                                                     const float* __restrict__ bias,
                                                     const float* __restrict__ resid,
                                                     void* __restrict__ Cout,
                                                     int M, int N, int K) {
    __shared__ ushort_t As[128 * 64];
    __shared__ ushort_t Bs[128 * 64];

    int tid = threadIdx.x;
    int wave = tid >> 6, lane = tid & 63;
    int m0 = blockIdx.x * 128, n0 = blockIdx.y * 128;
    int l8 = lane >> 3, c8 = lane & 7;
    int cg = c8 ^ l8;

    const ushort_t* gA = A  + (size_t)(m0 + 32 * wave + l8) * K + cg * 8;
    const ushort_t* gB = Bt + (size_t)(n0 + 32 * wave + l8) * K + cg * 8;
    ushort_t* lA = As + (32 * wave) * 64;
    ushort_t* lB = Bs + (32 * wave) * 64;

    f32x4 acc[4][4];
    #pragma unroll
    for (int i = 0; i < 4; i++)
        #pragma unroll
        for (int j = 0; j < 4; j++) acc[i][j] = (f32x4){0.f, 0.f, 0.f, 0.f};

    int wm = (wave >> 1) * 64, wn = (wave & 1) * 64;
    int fm = lane & 15;
    int fk = (lane >> 4) * 8;
    int swz = (fm & 7) * 8;

    for (int k0 = 0; k0 < K; k0 += 64) {
        __syncthreads();
        #pragma unroll
        for (int c = 0; c < 4; c++) {
            load_lds16(gA + (size_t)(8 * c) * K, lA + (8 * c) * 64);
            load_lds16(gB + (size_t)(8 * c) * K, lB + (8 * c) * 64);
        }
        gA += 64; gB += 64;
        __syncthreads();

        #pragma unroll
        for (int kh = 0; kh < 2; kh++) {
            int kk = kh * 32;
            bf16x8 af[4], bfr[4];
            #pragma unroll
            for (int i = 0; i < 4; i++)
                af[i] = *(const bf16x8*)&As[(wm + 16 * i + fm) * 64 + ((kk + fk) ^ swz)];
            #pragma unroll
            for (int j = 0; j < 4; j++)
                bfr[j] = *(const bf16x8*)&Bs[(wn + 16 * j + fm) * 64 + ((kk + fk) ^ swz)];
            #pragma unroll
            for (int i = 0; i < 4; i++)
                #pragma unroll
                for (int j = 0; j < 4; j++)
                    acc[i][j] = __builtin_amdgcn_mfma_f32_16x16x32_bf16(af[i], bfr[j], acc[i][j], 0, 0, 0);
        }
    }

    int col_l = lane & 15, row_l = (lane >> 4) * 4;
    #pragma unroll
    for (int i = 0; i < 4; i++) {
        #pragma unroll
        for (int j = 0; j < 4; j++) {
            int col = n0 + wn + 16 * j + col_l;
            float bia = bias ? bias[col] : 0.f;
            #pragma unroll
            for (int r = 0; r < 4; r++) {
                int row = m0 + wm + 16 * i + row_l + r;
                float c = acc[i][j][r] + bia;
                if (RELU) c = fmaxf(c, 0.f);
                if (resid) c += resid[(size_t)row * N + col];
                if (OUTMODE == 1)
                    ((ushort_t*)Cout)[(size_t)row * N + col] = f2bf(c);
                else
                    ((float*)Cout)[(size_t)row * N + col] = c;
            }
        }
    }
}

// ---------------- split-K bf16 GEMM, BK=64 (grid: M/128, N/128, nsplit) ----------
__global__ __launch_bounds__(256) void gemm_splitk(const ushort_t* __restrict__ A,
                                                   const ushort_t* __restrict__ Bt,
                                                   ushort_t* __restrict__ P,
                                                   int M, int N, int K, int nsplit) {
    __shared__ ushort_t As[128 * 64];
    __shared__ ushort_t Bs[128 * 64];

    int tid = threadIdx.x;
    int wave = tid >> 6, lane = tid & 63;
    int m0 = blockIdx.x * 128, n0 = blockIdx.y * 128;
    int klen = K / nsplit, kbeg = blockIdx.z * klen;
    int l8 = lane >> 3, c8 = lane & 7;
    int cg = c8 ^ l8;

    const ushort_t* gA = A  + (size_t)(m0 + 32 * wave + l8) * K + kbeg + cg * 8;
    const ushort_t* gB = Bt + (size_t)(n0 + 32 * wave + l8) * K + kbeg + cg * 8;
    ushort_t* lA = As + (32 * wave) * 64;
    ushort_t* lB = Bs + (32 * wave) * 64;

    f32x4 acc[4][4];
    #pragma unroll
    for (int i = 0; i < 4; i++)
        #pragma unroll
        for (int j = 0; j < 4; j++) acc[i][j] = (f32x4){0.f, 0.f, 0.f, 0.f};

    int wm = (wave >> 1) * 64, wn = (wave & 1) * 64;
    int fm = lane & 15;
    int fk = (lane >> 4) * 8;
    int swz = (fm & 7) * 8;

    for (int k0 = 0; k0 < klen; k0 += 64) {
        __syncthreads();
        #pragma unroll
        for (int c = 0; c < 4; c++) {
            load_lds16(gA + (size_t)(8 * c) * K, lA + (8 * c) * 64);
            load_lds16(gB + (size_t)(8 * c) * K, lB + (8 * c) * 64);
        }
        gA += 64; gB += 64;
        __syncthreads();

        #pragma unroll
        for (int kh = 0; kh < 2; kh++) {
            int kk = kh * 32;
            bf16x8 af[4], bfr[4];
            #pragma unroll
            for (int i = 0; i < 4; i++)
                af[i] = *(const bf16x8*)&As[(wm + 16 * i + fm) * 64 + ((kk + fk) ^ swz)];
            #pragma unroll
            for (int j = 0; j < 4; j++)
                bfr[j] = *(const bf16x8*)&Bs[(wn + 16 * j + fm) * 64 + ((kk + fk) ^ swz)];
            #pragma unroll
            for (int i = 0; i < 4; i++)
                #pragma unroll
                for (int j = 0; j < 4; j++)
                    acc[i][j] = __builtin_amdgcn_mfma_f32_16x16x32_bf16(af[i], bfr[j], acc[i][j], 0, 0, 0);
        }
    }

    ushort_t* Pz = P + (size_t)blockIdx.z * M * N;
    int col_l = lane & 15, row_l = (lane >> 4) * 4;
    #pragma unroll
    for (int i = 0; i < 4; i++)
        #pragma unroll
        for (int j = 0; j < 4; j++) {
            int col = n0 + wn + 16 * j + col_l;
            #pragma unroll
            for (int r = 0; r < 4; r++) {
                int row = m0 + wm + 16 * i + row_l + r;
                Pz[(size_t)row * N + col] = f2bf(acc[i][j][r]);
            }
        }
}

// out = sum_z P[z] + x2 + b2   (2 partials)
__global__ __launch_bounds__(256) void ffn2_reduce(const ushort_t* __restrict__ P,
                                                   const float* __restrict__ x2,
                                                   const float* __restrict__ b2,
                                                   float* __restrict__ out) {
    int row = blockIdx.x, t = threadIdx.x;
    const size_t MN = (size_t)ROWS * D_MODEL;
    size_t off = (size_t)row * D_MODEL + (t << 2);
    float4 acc = *(const float4*)&x2[off];
    float4 bb  = *(const float4*)&b2[t << 2];
    acc.x += bb.x; acc.y += bb.y; acc.z += bb.z; acc.w += bb.w;
    #pragma unroll
    for (int s = 0; s < 2; s++) {
        ushort4 u = *(const ushort4*)&P[s * MN + off];
        acc.x += bf2f(u.x); acc.y += bf2f(u.y);
        acc.z += bf2f(u.z); acc.w += bf2f(u.w);
    }
    *(float4*)&out[off] = acc;
}

// ---------------- bf16 MFMA GEMM, 128x64 tile, BK=64 (grid: M/128, N/64) ----------
template<bool RELU>
__global__ __launch_bounds__(256) void gemm_mfma_64(const ushort_t* __restrict__ A,
                                                    const ushort_t* __restrict__ Bt,
                                                    const float* __restrict__ bias,
                                                    const float* __restrict__ resid,
                                                    float* __restrict__ Cout,
                                                    int M, int N, int K) {
    __shared__ ushort_t As[128 * 64];
    __shared__ ushort_t Bs[64 * 64];

    int tid = threadIdx.x;
    int wave = tid >> 6, lane = tid & 63;
    int m0 = blockIdx.x * 128, n0 = blockIdx.y * 64;
    int l8 = lane >> 3, c8 = lane & 7;
    int cg = c8 ^ l8;

    const ushort_t* gA = A  + (size_t)(m0 + 32 * wave + l8) * K + cg * 8;
    const ushort_t* gB = Bt + (size_t)(n0 + 16 * wave + l8) * K + cg * 8;
    ushort_t* lA = As + (32 * wave) * 64;
    ushort_t* lB = Bs + (16 * wave) * 64;

    f32x4 acc[2][4];
    #pragma unroll
    for (int i = 0; i < 2; i++)
        #pragma unroll
        for (int j = 0; j < 4; j++) acc[i][j] = (f32x4){0.f, 0.f, 0.f, 0.f};

    int wm = 32 * wave;
    int fm = lane & 15;
    int fk = (lane >> 4) * 8;
    int swz = (fm & 7) * 8;

    for (int k0 = 0; k0 < K; k0 += 64) {
        __syncthreads();
        #pragma unroll
        for (int c = 0; c < 4; c++)
            load_lds16(gA + (size_t)(8 * c) * K, lA + (8 * c) * 64);
        #pragma unroll
        for (int c = 0; c < 2; c++)
            load_lds16(gB + (size_t)(8 * c) * K, lB + (8 * c) * 64);
        gA += 64; gB += 64;
        __syncthreads();

        #pragma unroll
        for (int kh = 0; kh < 2; kh++) {
            int kk = kh * 32;
            bf16x8 af[2], bfr[4];
            #pragma unroll
            for (int i = 0; i < 2; i++)
                af[i] = *(const bf16x8*)&As[(wm + 16 * i + fm) * 64 + ((kk + fk) ^ swz)];
            #pragma unroll
            for (int j = 0; j < 4; j++)
                bfr[j] = *(const bf16x8*)&Bs[(16 * j + fm) * 64 + ((kk + fk) ^ swz)];
            #pragma unroll
            for (int i = 0; i < 2; i++)
                #pragma unroll
                for (int j = 0; j < 4; j++)
                    acc[i][j] = __builtin_amdgcn_mfma_f32_16x16x32_bf16(af[i], bfr[j], acc[i][j], 0, 0, 0);
        }
    }

    int col_l = lane & 15, row_l = (lane >> 4) * 4;
    #pragma unroll
    for (int i = 0; i < 2; i++) {
        #pragma unroll
        for (int j = 0; j < 4; j++) {
            int col = n0 + 16 * j + col_l;
            float bia = bias ? bias[col] : 0.f;
            #pragma unroll
            for (int r = 0; r < 4; r++) {
                int row = m0 + wm + 16 * i + row_l + r;
                float c = acc[i][j][r] + bia;
                if (RELU) c = fmaxf(c, 0.f);
                if (resid) c += resid[(size_t)row * N + col];
                Cout[(size_t)row * N + col] = c;
            }
        }
    }
}

// ---------------- MFMA flash attention over COMPACTED keys, S^T form ----------------
__global__ __launch_bounds__(256) void fattn_mfma(const ushort_t* __restrict__ Q,
                                                  const ushort_t* __restrict__ K2,
                                                  const ushort_t* __restrict__ Vt2,
                                                  const int* __restrict__ nunb,
                                                  ushort_t* __restrict__ O) {
    __shared__ ushort_t Ks[64 * 64];    // [k][d], chunk-swizzled
    __shared__ ushort_t Vs[64 * 64];    // [d][k], chunk-swizzled
    __shared__ ushort_t Pt[128 * 68];   // [q][k], padded (+4)

    int tid = threadIdx.x, wave = tid >> 6, lane = tid & 63;
    int qt = blockIdx.x, h = blockIdx.y, b = blockIdx.z;
    int q0 = qt * 128;
    int l8 = lane >> 3, c8 = lane & 7;
    int cg = c8 ^ l8;

    const int nun = nunb[b];
    const int ntiles = (nun + 63) >> 6;

    const ushort_t* Kg = K2 + ((size_t)(b * SEQ)) * D_MODEL + h * 64;
    const ushort_t* Vg = Vt2 + ((size_t)(b * 1024 + h * 64)) * SEQ;

    int fm = lane & 15, fq = lane >> 4;
    int fk = fq * 8;
    int swz = (fm & 7) * 8;
    const float C2 = 0.18033688f;       // 0.125 * log2(e)

    bf16x8 qf[2][2];
    #pragma unroll
    for (int qg = 0; qg < 2; qg++) {
        int row = q0 + qg * 64 + wave * 16 + fm;
        const ushort_t* qr = Q + (size_t)(b * SEQ + row) * D_MODEL + h * 64;
        qf[qg][0] = *(const bf16x8*)&qr[fk];
        qf[qg][1] = *(const bf16x8*)&qr[32 + fk];
    }

    float l_acc[2] = {0.f, 0.f};
    f32x4 acc_o[2][4];
    #pragma unroll
    for (int qg = 0; qg < 2; qg++)
        #pragma unroll
        for (int j = 0; j < 4; j++) acc_o[qg][j] = (f32x4){0.f, 0.f, 0.f, 0.f};

    for (int kt = 0; kt < ntiles; kt++) {
        int k0 = kt * 64;
        __syncthreads();
        #pragma unroll
        for (int c = 0; c < 2; c++) {
            int row = c * 32 + wave * 8 + l8;
            load_lds16(Kg + (size_t)(k0 + row) * D_MODEL + cg * 8, &Ks[(c * 32 + wave * 8) * 64]);
            load_lds16(Vg + (size_t)row * SEQ + k0 + cg * 8,        &Vs[(c * 32 + wave * 8) * 64]);
        }
        __syncthreads();

        f32x4 sT[2][4];
        #pragma unroll
        for (int qg = 0; qg < 2; qg++)
            #pragma unroll
            for (int jk = 0; jk < 4; jk++) sT[qg][jk] = (f32x4){0.f, 0.f, 0.f, 0.f};
        #pragma unroll
        for (int kh = 0; kh < 2; kh++) {
            bf16x8 kf[4];
            #pragma unroll
            for (int jk = 0; jk < 4; jk++)
                kf[jk] = *(const bf16x8*)&Ks[(16 * jk + fm) * 64 + ((kh * 32 + fk) ^ swz)];
            #pragma unroll
            for (int qg = 0; qg < 2; qg++)
                #pragma unroll
                for (int jk = 0; jk < 4; jk++)
                    sT[qg][jk] = __builtin_amdgcn_mfma_f32_16x16x32_bf16(kf[jk], qf[qg][kh], sT[qg][jk], 0, 0, 0);
        }

        if (k0 + 64 <= nun) {
            #pragma unroll
            for (int qg = 0; qg < 2; qg++)
                #pragma unroll
                for (int jk = 0; jk < 4; jk++) {
                    #pragma unroll
                    for (int r = 0; r < 4; r++) {
                        float p = exp2f(sT[qg][jk][r] * C2);
                        sT[qg][jk][r] = p;
                        l_acc[qg] += p;
                    }
                }
        } else {
            #pragma unroll
            for (int qg = 0; qg < 2; qg++)
                #pragma unroll
                for (int jk = 0; jk < 4; jk++) {
                    int kb = k0 + 16 * jk + 4 * fq;
                    #pragma unroll
                    for (int r = 0; r < 4; r++) {
                        float bias = (kb + r < nun) ? 0.f : -1000.f;
                        float p = exp2f(fmaf(sT[qg][jk][r], C2, bias));
                        sT[qg][jk][r] = p;
                        l_acc[qg] += p;
                    }
                }
        }

        #pragma unroll
        for (int qg = 0; qg < 2; qg++) {
            ushort_t* prow = &Pt[(qg * 64 + wave * 16 + fm) * 68];
            #pragma unroll
            for (int jk = 0; jk < 4; jk++) {
                unsigned u0 = __float_as_uint(sT[qg][jk][0]) + 0x8000u;
                unsigned u1 = __float_as_uint(sT[qg][jk][1]) + 0x8000u;
                unsigned u2 = __float_as_uint(sT[qg][jk][2]) + 0x8000u;
                unsigned u3 = __float_as_uint(sT[qg][jk][3]) + 0x8000u;
                uint2 pk;
                pk.x = __builtin_amdgcn_perm(u1, u0, 0x07060302u);
                pk.y = __builtin_amdgcn_perm(u3, u2, 0x07060302u);
                *(uint2*)&prow[16 * jk + 4 * fq] = pk;
            }
        }
        __syncthreads();

        #pragma unroll
        for (int kh = 0; kh < 2; kh++) {
            bf16x8 vf[4];
            #pragma unroll
            for (int j = 0; j < 4; j++)
                vf[j] = *(const bf16x8*)&Vs[(16 * j + fm) * 64 + ((kh * 32 + fk) ^ swz)];
            #pragma unroll
            for (int qg = 0; qg < 2; qg++) {
                bf16x8 pf = *(const bf16x8*)&Pt[(qg * 64 + wave * 16 + fm) * 68 + kh * 32 + fk];
                #pragma unroll
                for (int j = 0; j < 4; j++)
                    acc_o[qg][j] = __builtin_amdgcn_mfma_f32_16x16x32_bf16(pf, vf[j], acc_o[qg][j], 0, 0, 0);
            }
        }
    }

    #pragma unroll
    for (int qg = 0; qg < 2; qg++) {
        float l_full = l_acc[qg];
        l_full += __shfl_xor(l_full, 16);
        l_full += __shfl_xor(l_full, 32);
        #pragma unroll
        for (int r = 0; r < 4; r++) {
            float lr = __shfl(l_full, fq * 4 + r);
            float inv = 1.0f / lr;
            int row = q0 + qg * 64 + wave * 16 + fq * 4 + r;
            #pragma unroll
            for (int j = 0; j < 4; j++) {
                int col = h * 64 + 16 * j + fm;
                O[(size_t)(b * SEQ + row) * D_MODEL + col] = f2bf(acc_o[qg][j][r] * inv);
            }
        }
    }
}

// ---------------- launch ----------------
extern "C" void kernel_launch(void* const* d_in, const int* in_sizes, int n_in,
                              void* d_out, int out_size, void* d_ws, size_t ws_size,
                              hipStream_t stream) {
    const float* x    = (const float*)d_in[0];
    const int*   mask = (const int*)  d_in[1];
    const float* wq   = (const float*)d_in[2];
    const float* wk   = (const float*)d_in[3];
    const float* wv   = (const float*)d_in[4];
    const float* wo   = (const float*)d_in[5];
    const float* w1   = (const float*)d_in[6];
    const float* b1   = (const float*)d_in[7];
    const float* w2   = (const float*)d_in[8];
    const float* b2   = (const float*)d_in[9];
    const float* ln1a = (const float*)d_in[10];
    const float* ln1b = (const float*)d_in[11];
    const float* ln2a = (const float*)d_in[12];
    const float* ln2b = (const float*)d_in[13];
    float* out = (float*)d_out;

    char* ws = (char*)d_ws;
    const size_t MB = 1024 * 1024;
    float*    x2    = (float*)   (ws + 0 * MB);    // 16 MB (hosts K2/Vt2 pre-WO)
    ushort_t* K2    = (ushort_t*)(ws + 0 * MB);    // 8 MB  (dead before x2 written)
    ushort_t* Vt2   = (ushort_t*)(ws + 8 * MB);    // 8 MB
    ushort_t* hbf   = (ushort_t*)(ws + 16 * MB);   // 8 MB (LN1/attn/LN2 out)
    ushort_t* qbf   = (ushort_t*)(ws + 24 * MB);   // 8 MB
    ushort_t* hg    = (ushort_t*)(ws + 40 * MB);   // 8 MB (compacted LN1 rows)
    ushort_t* ffbf  = (ushort_t*)(ws + 48 * MB);   // 32 MB (FFN1 out)
    ushort_t* wqkvt = (ushort_t*)(ws + 80 * MB);   // 6 MB: wq|wk|wv transposed
    ushort_t* wot   = (ushort_t*)(ws + 86 * MB);   // 2 MB
    ushort_t* w1t   = (ushort_t*)(ws + 88 * MB);   // 8 MB
    ushort_t* w2t   = (ushort_t*)(ws + 96 * MB);   // 8 MB
    int*      idxb  = (int*)     (ws + 104 * MB);
    int*      nunb  = (int*)     (ws + 104 * MB + 64 * 1024);
    ushort_t* pbuf  = (ushort_t*)(ws + 16 * MB);   // 16 MB splitk partials (reuse)

    ushort_t* wqt = wqkvt;
    ushort_t* wkt = wqkvt + (size_t)1024 * 1024;
    ushort_t* wvt = wqkvt + (size_t)2 * 1024 * 1024;

    dim3 blk(256);

    transpose4_bf16_kernel<<<dim3(16, 16, 4), blk, 0, stream>>>(wq, wk, wv, wo, wqt, wkt, wvt, wot);
    transpose_ffn_kernel<<<dim3(1024, 2), blk, 0, stream>>>(w1, w2, w1t, w2t);
    mask_scan_kernel<<<BATCH, blk, 0, stream>>>(mask, idxb, nunb);

    ln_kernel<<<ROWS, blk, 0, stream>>>(x, ln1a, ln1b, hbf);

    // compact LN1 rows for the K/V GEMM
    hgather_kernel<<<dim3(SEQ, BATCH), blk, 0, stream>>>(hbf, idxb, nunb, hg);

    // unified QKV: Q over all rows; K/V over compacted rows, V written transposed
    gemm_qkv<<<dim3(32, 24), blk, 0, stream>>>(hbf, hg, wqkvt, nunb, qbf, K2, Vt2);

    dim3 g_attn(SEQ / 128, NUM_HEADS, BATCH);
    fattn_mfma<<<g_attn, blk, 0, stream>>>(qbf, K2, Vt2, nunb, hbf);

    // x2 = x + attn @ wo
    dim3 g_wo(ROWS / 128, D_MODEL / 64);
    gemm_mfma_64<false><<<g_wo, blk, 0, stream>>>(hbf, wot, nullptr, x, x2, ROWS, D_MODEL, D_MODEL);

    ln_kernel<<<ROWS, blk, 0, stream>>>(x2, ln2a, ln2b, hbf);

    // ff = relu(h2 @ w1 + b1)
    dim3 g_ff1(ROWS / 128, D_HIDDEN / 128);
    gemm_mfma_128<true, 1><<<g_ff1, blk, 0, stream>>>(hbf, w1t, b1, nullptr, ffbf,
                                                      ROWS, D_HIDDEN, D_MODEL);

    // FFN2 split-K=2 + fused reduce
    dim3 g_ff2(ROWS / 128, D_MODEL / 128, 2);
    gemm_splitk<<<g_ff2, blk, 0, stream>>>(ffbf, w2t, pbuf, ROWS, D_MODEL, D_HIDDEN, 2);
    ffn2_reduce<<<ROWS, blk, 0, stream>>>(pbuf, x2, b2, out);
}